// Round 18
// baseline (186.079 us; speedup 1.0000x reference)
//
#include <hip/hip_runtime.h>
#include <hip/hip_bf16.h>

#define NN 768
#define MD 1024
#define NPAIR 295296            // 768*769/2
#define NPBLK2 2307             // fallback kernel grid
#define NSTRIP 18816            // sum_{g<48} 16*(48-g)
#define NSBLK 2352              // NSTRIP / 8 strips per block (4 waves x 2)

typedef __attribute__((ext_vector_type(8))) short s16x8;
typedef __attribute__((ext_vector_type(4))) float f32x4;
typedef __attribute__((ext_vector_type(2))) float f32x2;
typedef __attribute__((ext_vector_type(2))) __bf16 b16x2;

__device__ __forceinline__ ushort bf16_rn(float f) {
    uint u = __builtin_bit_cast(uint, f);
    u += 0x7FFFu + ((u >> 16) & 1u);
    return (ushort)(u >> 16);
}

// inverse triangular index (fallback kernel only)
__device__ __forceinline__ void ptoij(int p, int& io, int& jo) {
    const float disc = (float)(1537 * 1537 - 8 * p);
    int i = (int)((1537.0f - sqrtf(disc)) * 0.5f);
    i = i < 0 ? 0 : (i > 767 ? 767 : i);
    while (i > 0 && p < i * (1537 - i) / 2) --i;
    while (i < 767 && p >= (i + 1) * (1536 - i) / 2) ++i;
    io = i;
    jo = i + (p - i * (1537 - i) / 2);
}

// ---------- fused one-time prep: WF + ECF + strip table + EA -------------------
// blocks [0,64):   W2 -> bf16 fragment-major WF
// blocks [64,448): EC factors bf16 fragment-major ECF
// blocks [448,592): strip table  stab[slot] = (i<<6)|jg
// blocks [592,3664): EA rows f32: EA[i][m] = 2^(-(a_m x_i + b_m) log2e)
__global__ __launch_bounds__(256) void prep_all(
    const float* __restrict__ x,  const float* __restrict__ W1,
    const float* __restrict__ b1, const float* __restrict__ W2,
    ushort* __restrict__ WF, ushort* __restrict__ ECF,
    int* __restrict__ stab, float* __restrict__ EAg)
{
    const int b = blockIdx.x;
    const float NL2E = -1.4426950408889634f;
    if (b < 64) {                                    // --- w2frag ---
        const int id = b * 256 + threadIdx.x;        // 0..16383
        const int lane = id & 63;
        const int f = id >> 6;
        const int tn = f & 7;
        const int ks = (f >> 3) & 1;
        const int c  = f >> 4;
        const int k = tn * 16 + (lane & 15);
        const int m = c * 64 + ks * 32 + (lane >> 4) * 8;
        const float4 a = *reinterpret_cast<const float4*>(W2 + k * MD + m);
        const float4 bb = *reinterpret_cast<const float4*>(W2 + k * MD + m + 4);
        const float w[8] = {a.x, a.y, a.z, a.w, bb.x, bb.y, bb.z, bb.w};
        s16x8 h;
#pragma unroll
        for (int e = 0; e < 8; ++e) h[e] = (short)bf16_rn(w[e]);
        *reinterpret_cast<s16x8*>(WF + id * 8) = h;
    } else if (b < 448) {                            // --- ecfprep ---
        const int id = (b - 64) * 256 + threadIdx.x; // 0..98303
        const int j = id >> 7;
        const int m8 = id & 127;
        const float xj = x[j];
        const int mbase = m8 * 8;
        s16x8 h;
#pragma unroll
        for (int e = 0; e < 8; ++e) {
            const float cm = W1[(mbase + e) * 2 + 1];
            h[e] = (short)bf16_rn(__builtin_amdgcn_exp2f(cm * xj * NL2E));
        }
        const int c    = mbase >> 6;
        const int ks   = (mbase >> 5) & 1;
        const int l4   = (mbase & 31) >> 3;
        const int lane = l4 * 16 + (j & 15);
        const int off  = (j >> 4) * 16384 + c * 1024 + ks * 512 + lane * 8;
        *reinterpret_cast<s16x8*>(ECF + off) = h;
    } else if (b < 592) {                            // --- strip table ---
        const int id = (b - 448) * 256 + threadIdx.x;
        if (id < 768 * 48) {
            const int i = id / 48;
            const int q = id - i * 48;
            const int g = i >> 4;
            if (q >= g) {
                const int slot = 8 * g * (97 - g) + (i & 15) * (48 - g) + (q - g);
                stab[slot] = (i << 6) | q;
            }
        }
    } else {                                         // --- eaprep ---
        const int id = (b - 592) * 256 + threadIdx.x; // 0..786431
        const int i = id >> 10;
        const int m = id & 1023;
        const float2 w = reinterpret_cast<const float2*>(W1)[m];
        EAg[id] = __builtin_amdgcn_exp2f(fmaf(w.x, x[i], b1[m]) * NL2E);
    }
}

// ---- strip-kernel macros (ambient locals) --------------------------------------
#define LOADB_T(cc, ks)                                                      \
    {                                                                        \
        const ushort* wb_ = WF + (cc) * 8192 + (ks) * 4096 + lane * 8;       \
        _Pragma("unroll")                                                    \
        for (int tn_ = 0; tn_ < 8; ++tn_)                                    \
            bh[tn_] = *reinterpret_cast<const s16x8*>(wb_ + tn_ * 512);      \
    }

#define LOADEC_S(cc, ks, dst)                                                \
    {                                                                        \
        const int o_ = (cc) * 1024 + (ks) * 512 + lane * 8;                  \
        dst[0] = *reinterpret_cast<const s16x8*>(ec0base + o_);              \
        dst[1] = *reinterpret_cast<const s16x8*>(ec1base + o_);              \
    }

// sigma = rcp(1 + EA*EC): one transcendental per value
#define SIG_ONE(eabase, ecv, dst_ah)                                         \
    {                                                                        \
        const f32x4 ea0_ = *reinterpret_cast<const f32x4*>(eabase + m0_);    \
        const f32x4 ea1_ = *reinterpret_cast<const f32x4*>(eabase + m0_ + 4);\
        union { s16x8 v; uint u[4]; } ec_;                                   \
        ec_.v = ecv;                                                         \
        union { s16x8 v; uint u[4]; } fr_;                                   \
        _Pragma("unroll")                                                    \
        for (int h_ = 0; h_ < 4; ++h_) {                                     \
            const uint uu_ = ec_.u[h_];                                      \
            const float el_ = __builtin_bit_cast(float, uu_ << 16);          \
            const float eh_ = __builtin_bit_cast(float, uu_ & 0xFFFF0000u);  \
            const float ga_ = (h_ < 2) ? ea0_[2 * h_] : ea1_[2 * h_ - 4];    \
            const float gb_ = (h_ < 2) ? ea0_[2 * h_ + 1] : ea1_[2 * h_ - 3];\
            const float t0_ = fmaf(el_, ga_, 1.0f);                          \
            const float t1_ = fmaf(eh_, gb_, 1.0f);                          \
            b16x2 p_;                                                        \
            p_.x = (__bf16)__builtin_amdgcn_rcpf(t0_);                       \
            p_.y = (__bf16)__builtin_amdgcn_rcpf(t1_);                       \
            fr_.u[h_] = __builtin_bit_cast(uint, p_);                        \
        }                                                                    \
        dst_ah = fr_.v;                                                      \
    }

#define SIG_S(cc, ks_, ec)                                                   \
    {                                                                        \
        const int m0_ = (cc) * 64 + (ks_) * 32 + l4 * 8;                     \
        SIG_ONE(ea0base, ec[0], ah[0]);                                      \
        SIG_ONE(ea1base, ec[1], ah[1]);                                      \
    }

#define MFMA_T()                                                             \
    {                                                                        \
        __builtin_amdgcn_s_setprio(1);                                       \
        _Pragma("unroll")                                                    \
        for (int tm_ = 0; tm_ < 2; ++tm_)                                    \
            _Pragma("unroll")                                                \
            for (int tn_ = 0; tn_ < 8; ++tn_)                                \
                acc[tm_][tn_] = __builtin_amdgcn_mfma_f32_16x16x32_bf16(     \
                    ah[tm_], bh[tn_], acc[tm_][tn_], 0, 0, 0);               \
        __builtin_amdgcn_s_setprio(0);                                       \
    }

// ---------- main: 2 strips/wave (32 pairs), tables, zero LDS, zero barriers ----
__global__ __launch_bounds__(256, 3) void mlp_strip(
    const float* __restrict__ EAg, const ushort* __restrict__ ECF,
    const ushort* __restrict__ WF, const int* __restrict__ stab,
    const float* __restrict__ b2, const float* __restrict__ W3,
    const float* __restrict__ b3, float* __restrict__ K)
{
    const int t = threadIdx.x;
    const int lane = t & 63, wv = t >> 6;
    const int l15 = lane & 15, l4 = lane >> 4;

    const int gw = blockIdx.x * 4 + wv;
    const int s0 = stab[2 * gw], s1 = stab[2 * gw + 1];
    const int i0_ = s0 >> 6, jg0_ = s0 & 63;
    const int i1_ = s1 >> 6, jg1_ = s1 & 63;

    const float* ea0base = EAg + i0_ * MD;
    const float* ea1base = EAg + i1_ * MD;
    const ushort* ec0base = ECF + jg0_ * 16384;
    const ushort* ec1base = ECF + jg1_ * 16384;

    f32x4 acc[2][8];
#pragma unroll
    for (int a = 0; a < 2; ++a)
#pragma unroll
        for (int b = 0; b < 8; ++b) acc[a][b] = (f32x4){0.f, 0.f, 0.f, 0.f};

    s16x8 bh[8], ecA[2], ecB[2], ah[2];
    LOADB_T(0, 0);
    LOADEC_S(0, 0, ecA);

    for (int c = 0; c < 16; ++c) {
        LOADEC_S(c, 1, ecB);                 // flies over SIG0+MFMA0
        SIG_S(c, 0, ecA);                    // covers in-flight bh ks0
        MFMA_T();                            // consumes bh = ks0
        LOADB_T(c, 1);                       // refill bh with ks1 frags
        if (c < 15) LOADEC_S(c + 1, 0, ecA); // flies over SIG1+MFMA1
        SIG_S(c, 1, ecB);
        MFMA_T();                            // consumes bh = ks1
        if (c < 15) LOADB_T(c + 1, 0);
    }

    // epilogue: v = sum_k W3[k]*relu(h2 + b2[k]) + b3; reduce over 16 lanes (k)
    float w3v[8], b2v[8];
#pragma unroll
    for (int tn = 0; tn < 8; ++tn) {
        const int k = tn * 16 + l15;
        w3v[tn] = W3[k];
        b2v[tn] = b2[k];
    }
    const float b3v = b3[0];
#pragma unroll
    for (int tm = 0; tm < 2; ++tm) {
        const int iS  = (tm == 0) ? i0_ : i1_;
        const int jgS = (tm == 0) ? jg0_ : jg1_;
#pragma unroll
        for (int r = 0; r < 4; ++r) {
            float v = 0.f;
#pragma unroll
            for (int tn = 0; tn < 8; ++tn)
                v = fmaf(w3v[tn], fmaxf(acc[tm][tn][r] + b2v[tn], 0.f), v);
            v += __shfl_xor(v, 1, 16);
            v += __shfl_xor(v, 2, 16);
            v += __shfl_xor(v, 4, 16);
            v += __shfl_xor(v, 8, 16);
            if (l15 == 0) {
                const int j = jgS * 16 + l4 * 4 + r;
                if (j >= iS) K[iS * NN + j] = v + b3v;
            }
        }
    }
}

// ---------- fallback (R16 proven): pair-flattened, exp2-in-loop, zero barriers -
__global__ __launch_bounds__(256) void w2frag(const float* __restrict__ W2,
                                              ushort* __restrict__ WF)
{
    const int id = blockIdx.x * 256 + threadIdx.x;
    const int lane = id & 63;
    const int f = id >> 6;
    const int tn = f & 7;
    const int ks = (f >> 3) & 1;
    const int c  = f >> 4;
    const int k = tn * 16 + (lane & 15);
    const int m = c * 64 + ks * 32 + (lane >> 4) * 8;
    const float4 a = *reinterpret_cast<const float4*>(W2 + k * MD + m);
    const float4 b = *reinterpret_cast<const float4*>(W2 + k * MD + m + 4);
    const float w[8] = {a.x, a.y, a.z, a.w, b.x, b.y, b.z, b.w};
    s16x8 h;
#pragma unroll
    for (int e = 0; e < 8; ++e) h[e] = (short)bf16_rn(w[e]);
    *reinterpret_cast<s16x8*>(WF + id * 8) = h;
}

#define LOADB(cc, ks)                                                        \
    {                                                                        \
        const ushort* wb_ = WF + (cc) * 8192 + (ks) * 4096 + lane * 8;       \
        _Pragma("unroll")                                                    \
        for (int tn_ = 0; tn_ < 8; ++tn_)                                    \
            bh[tn_] = *reinterpret_cast<const s16x8*>(wb_ + tn_ * 512);      \
    }

#define SIG_HALF(cc, ks_)                                                    \
    {                                                                        \
        const int m0_ = (cc) * 64 + (ks_) * 32 + l4 * 8;                     \
        const f32x4 a0_ = *reinterpret_cast<const f32x4*>(&sa[m0_]);         \
        const f32x4 a1_ = *reinterpret_cast<const f32x4*>(&sa[m0_ + 4]);     \
        const f32x4 c0_ = *reinterpret_cast<const f32x4*>(&sc[m0_]);         \
        const f32x4 c1_ = *reinterpret_cast<const f32x4*>(&sc[m0_ + 4]);     \
        const f32x4 b0_ = *reinterpret_cast<const f32x4*>(&sb[m0_]);         \
        const f32x4 b1_ = *reinterpret_cast<const f32x4*>(&sb[m0_ + 4]);     \
        _Pragma("unroll")                                                    \
        for (int tm_ = 0; tm_ < 2; ++tm_) {                                  \
            const f32x2 xi2_ = (f32x2){xia[tm_], xia[tm_]};                  \
            const f32x2 xj2_ = (f32x2){xja[tm_], xja[tm_]};                  \
            const f32x2 one2_ = (f32x2){1.f, 1.f};                           \
            union { s16x8 v; uint u[4]; } fr_;                               \
            _Pragma("unroll")                                                \
            for (int h_ = 0; h_ < 4; ++h_) {                                 \
                f32x2 av_, cv_, bv_;                                         \
                if (h_ < 2) {                                                \
                    av_ = (f32x2){a0_[2 * h_], a0_[2 * h_ + 1]};             \
                    cv_ = (f32x2){c0_[2 * h_], c0_[2 * h_ + 1]};             \
                    bv_ = (f32x2){b0_[2 * h_], b0_[2 * h_ + 1]};             \
                } else {                                                     \
                    av_ = (f32x2){a1_[2 * h_ - 4], a1_[2 * h_ - 3]};         \
                    cv_ = (f32x2){c1_[2 * h_ - 4], c1_[2 * h_ - 3]};         \
                    bv_ = (f32x2){b1_[2 * h_ - 4], b1_[2 * h_ - 3]};         \
                }                                                            \
                const f32x2 u2_ = __builtin_elementwise_fma(                 \
                    xi2_, av_, __builtin_elementwise_fma(xj2_, cv_, bv_));   \
                f32x2 e2_;                                                   \
                e2_[0] = __builtin_amdgcn_exp2f(u2_[0]);                     \
                e2_[1] = __builtin_amdgcn_exp2f(u2_[1]);                     \
                const f32x2 t2_ = e2_ + one2_;                               \
                b16x2 p_;                                                    \
                p_.x = (__bf16)__builtin_amdgcn_rcpf(t2_[0]);                \
                p_.y = (__bf16)__builtin_amdgcn_rcpf(t2_[1]);                \
                fr_.u[h_] = __builtin_bit_cast(uint, p_);                    \
            }                                                                \
            ah[tm_] = fr_.v;                                                 \
        }                                                                    \
    }

#define MFMA_HALF()                                                          \
    {                                                                        \
        __builtin_amdgcn_s_setprio(1);                                       \
        _Pragma("unroll")                                                    \
        for (int tm_ = 0; tm_ < 2; ++tm_)                                    \
            _Pragma("unroll")                                                \
            for (int tn_ = 0; tn_ < 8; ++tn_)                                \
                acc[tm_][tn_] = __builtin_amdgcn_mfma_f32_16x16x32_bf16(     \
                    ah[tm_], bh[tn_], acc[tm_][tn_], 0, 0, 0);               \
        __builtin_amdgcn_s_setprio(0);                                       \
    }

__global__ __launch_bounds__(256, 3) void mlp_pairs_reg(
    const float* __restrict__ x,
    const float* __restrict__ W1, const float* __restrict__ b1,
    const ushort* __restrict__ WF,
    const float* __restrict__ b2, const float* __restrict__ W3,
    const float* __restrict__ b3, float* __restrict__ K)
{
    __shared__ __align__(16) float sa[MD], sc[MD], sb[MD];

    const int t = threadIdx.x;
    const int lane = t & 63;
    const int l15 = lane & 15, l4 = lane >> 4;
    const int wv = t >> 6;

    const float NL2E = -1.4426950408889634f;
    for (int m = t; m < MD; m += 256) {
        const float2 w = reinterpret_cast<const float2*>(W1)[m];
        sa[m] = w.x * NL2E;
        sc[m] = w.y * NL2E;
        sb[m] = b1[m] * NL2E;
    }

    const int pairbase = blockIdx.x * 128 + wv * 32;

    float xia[2], xja[2];
#pragma unroll
    for (int tm = 0; tm < 2; ++tm) {
        const int p = pairbase + tm * 16 + l15;
        if (p < NPAIR) {
            int i, j;
            ptoij(p, i, j);
            xia[tm] = x[i];
            xja[tm] = x[j];
        } else {
            xia[tm] = 0.f;
            xja[tm] = 0.f;
        }
    }

    f32x4 acc[2][8];
#pragma unroll
    for (int a = 0; a < 2; ++a)
#pragma unroll
        for (int b = 0; b < 8; ++b) acc[a][b] = (f32x4){0.f, 0.f, 0.f, 0.f};

    s16x8 bh[8];
    LOADB(0, 0);
    __syncthreads();

    s16x8 ah[2];
    for (int c = 0; c < 16; ++c) {
        SIG_HALF(c, 0);
        MFMA_HALF();
        LOADB(c, 1);
        SIG_HALF(c, 1);
        MFMA_HALF();
        if (c < 15) LOADB(c + 1, 0);
    }

    float w3v[8], b2v[8];
#pragma unroll
    for (int tn = 0; tn < 8; ++tn) {
        const int k = tn * 16 + l15;
        w3v[tn] = W3[k];
        b2v[tn] = b2[k];
    }
    const float b3v = b3[0];
#pragma unroll
    for (int tm = 0; tm < 2; ++tm)
#pragma unroll
        for (int r = 0; r < 4; ++r) {
            float v = 0.f;
#pragma unroll
            for (int tn = 0; tn < 8; ++tn)
                v = fmaf(w3v[tn], fmaxf(acc[tm][tn][r] + b2v[tn], 0.f), v);
            v += __shfl_xor(v, 1, 16);
            v += __shfl_xor(v, 2, 16);
            v += __shfl_xor(v, 4, 16);
            v += __shfl_xor(v, 8, 16);
            if (l15 == 0) {
                const int p = pairbase + tm * 16 + l4 * 4 + r;
                if (p < NPAIR) {
                    int i, j;
                    ptoij(p, i, j);
                    K[i * NN + j] = v + b3v;
                }
            }
        }
}

// ---------- Kernel 2: C = K^T K, symmetric — compute upper tiles, mirror -------
__global__ __launch_bounds__(256) void ktk(const float* __restrict__ K,
                                           float* __restrict__ C)
{
    const int b0 = blockIdx.x * 64;
    const int a0 = blockIdx.y * 64;
    if (b0 < a0) return;             // C symmetric: only tiles with b0 >= a0
    __shared__ float Ka[64][68];
    __shared__ float Kb[64][68];
    const int t  = threadIdx.x;
    const int tb = t & 15;
    const int ta = t >> 4;
    float acc[4][4];
#pragma unroll
    for (int u = 0; u < 4; u++)
#pragma unroll
        for (int v = 0; v < 4; v++) acc[u][v] = 0.f;
    const int kmax = a0 + 64;        // K[k][a]=0 for k>a; a0 <= b0
    for (int k0 = 0; k0 < kmax; k0 += 64) {
#pragma unroll
        for (int q = 0; q < 4; q++) {
            const int f  = t + q * 256;
            const int kk = f >> 4;
            const int c4 = (f & 15) * 4;
            *reinterpret_cast<float4*>(&Ka[kk][c4]) =
                *reinterpret_cast<const float4*>(K + (k0 + kk) * NN + a0 + c4);
            *reinterpret_cast<float4*>(&Kb[kk][c4]) =
                *reinterpret_cast<const float4*>(K + (k0 + kk) * NN + b0 + c4);
        }
        __syncthreads();
#pragma unroll 8
        for (int kk = 0; kk < 64; kk++) {
            const float4 av = *reinterpret_cast<const float4*>(&Ka[kk][ta * 4]);
            const float4 bv = *reinterpret_cast<const float4*>(&Kb[kk][tb * 4]);
            const float a4[4] = {av.x, av.y, av.z, av.w};
            const float b4[4] = {bv.x, bv.y, bv.z, bv.w};
#pragma unroll
            for (int u = 0; u < 4; u++)
#pragma unroll
                for (int v = 0; v < 4; v++)
                    acc[u][v] = fmaf(a4[u], b4[v], acc[u][v]);
        }
        __syncthreads();
    }
#pragma unroll
    for (int u = 0; u < 4; u++) {
        float4 o;
        o.x = acc[u][0]; o.y = acc[u][1]; o.z = acc[u][2]; o.w = acc[u][3];
        *reinterpret_cast<float4*>(C + (a0 + ta * 4 + u) * NN + b0 + tb * 4) = o;
    }
    if (b0 > a0) {                   // mirror tile: C[b][a] = C[a][b], coalesced
#pragma unroll
        for (int v = 0; v < 4; v++) {
            float4 o;
            o.x = acc[0][v]; o.y = acc[1][v]; o.z = acc[2][v]; o.w = acc[3][v];
            *reinterpret_cast<float4*>(C + (b0 + tb * 4 + v) * NN + a0 + ta * 4) = o;
        }
    }
}

extern "C" void kernel_launch(void* const* d_in, const int* in_sizes, int n_in,
                              void* d_out, int out_size, void* d_ws, size_t ws_size,
                              hipStream_t stream)
{
    const float* x  = (const float*)d_in[0];
    const float* W1 = (const float*)d_in[1];
    const float* b1 = (const float*)d_in[2];
    const float* W2 = (const float*)d_in[3];
    const float* b2 = (const float*)d_in[4];
    const float* W3 = (const float*)d_in[5];
    const float* b3 = (const float*)d_in[6];
    float* Kmat = (float*)d_ws;                       // 2,359,296 B
    float* C    = (float*)d_out;

    const size_t kBytes  = (size_t)NN * NN * sizeof(float);
    const size_t wBytes  = 262144;                              // WF
    const size_t eaB     = (size_t)NN * MD * sizeof(float);     // 3 MB
    const size_t ecB     = (size_t)48 * 16384 * sizeof(ushort); // 1.5 MB
    const size_t stB     = (size_t)NSTRIP * sizeof(int);        // 75 KB
    const size_t needTab = kBytes + wBytes + eaB + ecB + stB;   // ~7.4 MB
    const size_t needFB  = kBytes + wBytes;

    hipMemsetAsync(Kmat, 0, kBytes, stream);
    if (ws_size >= needTab) {
        ushort* WF  = (ushort*)((char*)d_ws + kBytes);
        float*  EAg = (float*)((char*)d_ws + kBytes + wBytes);
        ushort* ECF = (ushort*)((char*)d_ws + kBytes + wBytes + eaB);
        int*    stab = (int*)((char*)d_ws + kBytes + wBytes + eaB + ecB);
        prep_all<<<3664, 256, 0, stream>>>(x, W1, b1, W2, WF, ECF, stab, EAg);
        mlp_strip<<<NSBLK, 256, 0, stream>>>(EAg, ECF, WF, stab, b2, W3, b3, Kmat);
    } else if (ws_size >= needFB) {
        ushort* WF = (ushort*)((char*)d_ws + kBytes);
        w2frag<<<64, 256, 0, stream>>>(W2, WF);
        mlp_pairs_reg<<<NPBLK2, 256, 0, stream>>>(x, W1, b1, WF, b2, W3, b3, Kmat);
    }
    ktk<<<dim3(NN / 64, NN / 64), 256, 0, stream>>>(Kmat, C);
}

// Round 19
// 176.305 us; speedup vs baseline: 1.0554x; 1.0554x over previous
//
#include <hip/hip_runtime.h>
#include <hip/hip_bf16.h>

#define NN 768
#define MD 1024
#define NPAIR 295296            // 768*769/2
#define NPBLK2 2307             // fallback kernel grid

typedef __attribute__((ext_vector_type(8))) short s16x8;
typedef __attribute__((ext_vector_type(4))) float f32x4;
typedef __attribute__((ext_vector_type(2))) float f32x2;
typedef __attribute__((ext_vector_type(2))) __bf16 b16x2;

__device__ __forceinline__ ushort bf16_rn(float f) {
    uint u = __builtin_bit_cast(uint, f);
    u += 0x7FFFu + ((u >> 16) & 1u);
    return (ushort)(u >> 16);
}

// inverse triangular index (fallback kernel only)
__device__ __forceinline__ void ptoij(int p, int& io, int& jo) {
    const float disc = (float)(1537 * 1537 - 8 * p);
    int i = (int)((1537.0f - sqrtf(disc)) * 0.5f);
    i = i < 0 ? 0 : (i > 767 ? 767 : i);
    while (i > 0 && p < i * (1537 - i) / 2) --i;
    while (i < 767 && p >= (i + 1) * (1536 - i) / 2) ++i;
    io = i;
    jo = i + (p - i * (1537 - i) / 2);
}

#define GLOAD16(gsrc, ldst)                                                        \
    __builtin_amdgcn_global_load_lds(                                              \
        (const __attribute__((address_space(1))) void*)(gsrc),                     \
        (__attribute__((address_space(3))) void*)(ldst), 16, 0, 0)

// ---------- fused one-time prep: WF + ECF + EA (single launch) -----------------
// blocks [0,64):    W2 -> bf16 fragment-major WF
// blocks [64,448):  EC factors bf16 fragment-major ECF
// blocks [448,3520): EA rows f32: EA[i][m] = 2^(-(a_m x_i + b_m) log2e)
__global__ __launch_bounds__(256) void prep_all(
    const float* __restrict__ x,  const float* __restrict__ W1,
    const float* __restrict__ b1, const float* __restrict__ W2,
    ushort* __restrict__ WF, ushort* __restrict__ ECF,
    float* __restrict__ EAg)
{
    const int b = blockIdx.x;
    const float NL2E = -1.4426950408889634f;
    if (b < 64) {                                    // --- w2frag ---
        const int id = b * 256 + threadIdx.x;        // 0..16383
        const int lane = id & 63;
        const int f = id >> 6;
        const int tn = f & 7;
        const int ks = (f >> 3) & 1;
        const int c  = f >> 4;
        const int k = tn * 16 + (lane & 15);
        const int m = c * 64 + ks * 32 + (lane >> 4) * 8;
        const float4 a = *reinterpret_cast<const float4*>(W2 + k * MD + m);
        const float4 bb = *reinterpret_cast<const float4*>(W2 + k * MD + m + 4);
        const float w[8] = {a.x, a.y, a.z, a.w, bb.x, bb.y, bb.z, bb.w};
        s16x8 h;
#pragma unroll
        for (int e = 0; e < 8; ++e) h[e] = (short)bf16_rn(w[e]);
        *reinterpret_cast<s16x8*>(WF + id * 8) = h;
    } else if (b < 448) {                            // --- ecfprep ---
        const int id = (b - 64) * 256 + threadIdx.x; // 0..98303 (768 j x 128 m8)
        const int j = id >> 7;
        const int m8 = id & 127;
        const float xj = x[j];
        const int mbase = m8 * 8;
        s16x8 h;
#pragma unroll
        for (int e = 0; e < 8; ++e) {
            const float cm = W1[(mbase + e) * 2 + 1];
            h[e] = (short)bf16_rn(__builtin_amdgcn_exp2f(cm * xj * NL2E));
        }
        const int c    = mbase >> 6;
        const int ks   = (mbase >> 5) & 1;
        const int l4   = (mbase & 31) >> 3;
        const int lane = l4 * 16 + (j & 15);
        const int off  = (j >> 4) * 16384 + c * 1024 + ks * 512 + lane * 8;
        *reinterpret_cast<s16x8*>(ECF + off) = h;
    } else {                                         // --- eaprep ---
        const int id = (b - 448) * 256 + threadIdx.x; // 0..786431
        const int i = id >> 10;
        const int m = id & 1023;
        const float2 w = reinterpret_cast<const float2*>(W1)[m];
        EAg[id] = __builtin_amdgcn_exp2f(fmaf(w.x, x[i], b1[m]) * NL2E);
    }
}

// ---- table-kernel macros (ambient locals) --------------------------------------
#define LOADB_T(cc, ks)                                                      \
    {                                                                        \
        const ushort* wb_ = WF + (cc) * 8192 + (ks) * 4096 + lane * 8;       \
        _Pragma("unroll")                                                    \
        for (int tn_ = 0; tn_ < 8; ++tn_)                                    \
            bh[tn_] = *reinterpret_cast<const s16x8*>(wb_ + tn_ * 512);      \
    }

#define LOADEC(cc, ks, dst)                                                  \
    {                                                                        \
        const ushort* e_ = ECF + jg0 * 16384 + (cc) * 1024 + (ks) * 512 + lane * 8; \
        dst[0] = *reinterpret_cast<const s16x8*>(e_);                        \
        dst[1] = *reinterpret_cast<const s16x8*>(e_ + 16384);                \
    }

// sigma = rcp(1 + EA*EC): 1 transcendental per value (no exp2 in hot loop)
#define SIG_T(cc, ks_, ec)                                                   \
    {                                                                        \
        const int m0_ = (cc) * 64 + (ks_) * 32 + l4 * 8;                     \
        const f32x4 ea0_ = *reinterpret_cast<const f32x4*>(&EAl[m0_]);       \
        const f32x4 ea1_ = *reinterpret_cast<const f32x4*>(&EAl[m0_ + 4]);   \
        _Pragma("unroll")                                                    \
        for (int tm_ = 0; tm_ < 2; ++tm_) {                                  \
            union { s16x8 v; uint u[4]; } ec_;                               \
            ec_.v = ec[tm_];                                                 \
            union { s16x8 v; uint u[4]; } fr_;                               \
            _Pragma("unroll")                                                \
            for (int h_ = 0; h_ < 4; ++h_) {                                 \
                const uint uu_ = ec_.u[h_];                                  \
                const float el_ = __builtin_bit_cast(float, uu_ << 16);      \
                const float eh_ = __builtin_bit_cast(float, uu_ & 0xFFFF0000u); \
                const float ga_ = (h_ < 2) ? ea0_[2 * h_] : ea1_[2 * h_ - 4];     \
                const float gb_ = (h_ < 2) ? ea0_[2 * h_ + 1] : ea1_[2 * h_ - 3]; \
                const float t0_ = fmaf(el_, ga_, 1.0f);                      \
                const float t1_ = fmaf(eh_, gb_, 1.0f);                      \
                b16x2 p_;                                                    \
                p_.x = (__bf16)__builtin_amdgcn_rcpf(t0_);                   \
                p_.y = (__bf16)__builtin_amdgcn_rcpf(t1_);                   \
                fr_.u[h_] = __builtin_bit_cast(uint, p_);                    \
            }                                                                \
            ah[tm_] = fr_.v;                                                 \
        }                                                                    \
    }

#define MFMA_T()                                                             \
    {                                                                        \
        __builtin_amdgcn_s_setprio(1);                                       \
        _Pragma("unroll")                                                    \
        for (int tm_ = 0; tm_ < 2; ++tm_)                                    \
            _Pragma("unroll")                                                \
            for (int tn_ = 0; tn_ < 8; ++tn_)                                \
                acc[tm_][tn_] = __builtin_amdgcn_mfma_f32_16x16x32_bf16(     \
                    ah[tm_], bh[tn_], acc[tm_][tn_], 0, 0, 0);               \
        __builtin_amdgcn_s_setprio(0);                                       \
    }

// ---------- main (R17-proven): row-block (i,128 j), tables, zero loop barriers -
__global__ __launch_bounds__(256, 3) void mlp_tab(
    const float* __restrict__ EAg, const ushort* __restrict__ ECF,
    const ushort* __restrict__ WF,
    const float* __restrict__ b2, const float* __restrict__ W3,
    const float* __restrict__ b3, float* __restrict__ K)
{
    const int i  = blockIdx.y;
    const int j0 = blockIdx.x * 128;
    if (j0 + 127 < i) return;                 // fully below diagonal

    __shared__ __align__(16) float EAl[MD];   // 4 KB only

    const int t = threadIdx.x;
    const int lane = t & 63, wv = t >> 6;
    const int l15 = lane & 15, l4 = lane >> 4;

    const int jw  = j0 + wv * 32;             // wave's 32 j rows
    const int jg0 = jw >> 4;                  // first of two 16-j fragment groups

    // prologue: stage EA row (4KB) + first W2/EC frag loads
    GLOAD16(EAg + i * MD + wv * 256 + lane * 4, (char*)EAl + wv * 1024);

    f32x4 acc[2][8];
#pragma unroll
    for (int a = 0; a < 2; ++a)
#pragma unroll
        for (int b = 0; b < 8; ++b) acc[a][b] = (f32x4){0.f, 0.f, 0.f, 0.f};

    s16x8 bh[8], ecA[2], ecB[2], ah[2];
    LOADB_T(0, 0);
    LOADEC(0, 0, ecA);
    __syncthreads();                 // EAl resident (the ONLY barrier)

    for (int c = 0; c < 16; ++c) {
        LOADEC(c, 1, ecB);           // flies over SIG0+MFMA0
        SIG_T(c, 0, ecA);            // consumes ecA; covers in-flight bh ks0
        MFMA_T();                    // consumes bh = ks0
        LOADB_T(c, 1);               // refill bh with ks1 frags
        if (c < 15) LOADEC(c + 1, 0, ecA);   // flies over SIG1+MFMA1
        SIG_T(c, 1, ecB);
        MFMA_T();                    // consumes bh = ks1
        if (c < 15) LOADB_T(c + 1, 0);
    }

    // epilogue: v = sum_k W3[k]*relu(h2 + b2[k]) + b3; reduce over 16 lanes (k)
    float w3v[8], b2v[8];
#pragma unroll
    for (int tn = 0; tn < 8; ++tn) {
        const int k = tn * 16 + l15;
        w3v[tn] = W3[k];
        b2v[tn] = b2[k];
    }
    const float b3v = b3[0];
#pragma unroll
    for (int tm = 0; tm < 2; ++tm)
#pragma unroll
        for (int r = 0; r < 4; ++r) {
            float v = 0.f;
#pragma unroll
            for (int tn = 0; tn < 8; ++tn)
                v = fmaf(w3v[tn], fmaxf(acc[tm][tn][r] + b2v[tn], 0.f), v);
            v += __shfl_xor(v, 1, 16);
            v += __shfl_xor(v, 2, 16);
            v += __shfl_xor(v, 4, 16);
            v += __shfl_xor(v, 8, 16);
            if (l15 == 0) {
                const int j = jw + tm * 16 + l4 * 4 + r;
                if (j >= i) K[i * NN + j] = v + b3v;
            }
        }
}

// ---------- fallback (R16 proven): pair-flattened, exp2-in-loop, zero barriers -
__global__ __launch_bounds__(256) void w2frag(const float* __restrict__ W2,
                                              ushort* __restrict__ WF)
{
    const int id = blockIdx.x * 256 + threadIdx.x;
    const int lane = id & 63;
    const int f = id >> 6;
    const int tn = f & 7;
    const int ks = (f >> 3) & 1;
    const int c  = f >> 4;
    const int k = tn * 16 + (lane & 15);
    const int m = c * 64 + ks * 32 + (lane >> 4) * 8;
    const float4 a = *reinterpret_cast<const float4*>(W2 + k * MD + m);
    const float4 b = *reinterpret_cast<const float4*>(W2 + k * MD + m + 4);
    const float w[8] = {a.x, a.y, a.z, a.w, b.x, b.y, b.z, b.w};
    s16x8 h;
#pragma unroll
    for (int e = 0; e < 8; ++e) h[e] = (short)bf16_rn(w[e]);
    *reinterpret_cast<s16x8*>(WF + id * 8) = h;
}

#define LOADB(cc, ks)                                                        \
    {                                                                        \
        const ushort* wb_ = WF + (cc) * 8192 + (ks) * 4096 + lane * 8;       \
        _Pragma("unroll")                                                    \
        for (int tn_ = 0; tn_ < 8; ++tn_)                                    \
            bh[tn_] = *reinterpret_cast<const s16x8*>(wb_ + tn_ * 512);      \
    }

#define SIG_HALF(cc, ks_)                                                    \
    {                                                                        \
        const int m0_ = (cc) * 64 + (ks_) * 32 + l4 * 8;                     \
        const f32x4 a0_ = *reinterpret_cast<const f32x4*>(&sa[m0_]);         \
        const f32x4 a1_ = *reinterpret_cast<const f32x4*>(&sa[m0_ + 4]);     \
        const f32x4 c0_ = *reinterpret_cast<const f32x4*>(&sc[m0_]);         \
        const f32x4 c1_ = *reinterpret_cast<const f32x4*>(&sc[m0_ + 4]);     \
        const f32x4 b0_ = *reinterpret_cast<const f32x4*>(&sb[m0_]);         \
        const f32x4 b1_ = *reinterpret_cast<const f32x4*>(&sb[m0_ + 4]);     \
        _Pragma("unroll")                                                    \
        for (int tm_ = 0; tm_ < 2; ++tm_) {                                  \
            const f32x2 xi2_ = (f32x2){xia[tm_], xia[tm_]};                  \
            const f32x2 xj2_ = (f32x2){xja[tm_], xja[tm_]};                  \
            const f32x2 one2_ = (f32x2){1.f, 1.f};                           \
            union { s16x8 v; uint u[4]; } fr_;                               \
            _Pragma("unroll")                                                \
            for (int h_ = 0; h_ < 4; ++h_) {                                 \
                f32x2 av_, cv_, bv_;                                         \
                if (h_ < 2) {                                                \
                    av_ = (f32x2){a0_[2 * h_], a0_[2 * h_ + 1]};             \
                    cv_ = (f32x2){c0_[2 * h_], c0_[2 * h_ + 1]};             \
                    bv_ = (f32x2){b0_[2 * h_], b0_[2 * h_ + 1]};             \
                } else {                                                     \
                    av_ = (f32x2){a1_[2 * h_ - 4], a1_[2 * h_ - 3]};         \
                    cv_ = (f32x2){c1_[2 * h_ - 4], c1_[2 * h_ - 3]};         \
                    bv_ = (f32x2){b1_[2 * h_ - 4], b1_[2 * h_ - 3]};         \
                }                                                            \
                const f32x2 u2_ = __builtin_elementwise_fma(                 \
                    xi2_, av_, __builtin_elementwise_fma(xj2_, cv_, bv_));   \
                f32x2 e2_;                                                   \
                e2_[0] = __builtin_amdgcn_exp2f(u2_[0]);                     \
                e2_[1] = __builtin_amdgcn_exp2f(u2_[1]);                     \
                const f32x2 t2_ = e2_ + one2_;                               \
                b16x2 p_;                                                    \
                p_.x = (__bf16)__builtin_amdgcn_rcpf(t2_[0]);                \
                p_.y = (__bf16)__builtin_amdgcn_rcpf(t2_[1]);                \
                fr_.u[h_] = __builtin_bit_cast(uint, p_);                    \
            }                                                                \
            ah[tm_] = fr_.v;                                                 \
        }                                                                    \
    }

#define MFMA_HALF()                                                          \
    {                                                                        \
        __builtin_amdgcn_s_setprio(1);                                       \
        _Pragma("unroll")                                                    \
        for (int tm_ = 0; tm_ < 2; ++tm_)                                    \
            _Pragma("unroll")                                                \
            for (int tn_ = 0; tn_ < 8; ++tn_)                                \
                acc[tm_][tn_] = __builtin_amdgcn_mfma_f32_16x16x32_bf16(     \
                    ah[tm_], bh[tn_], acc[tm_][tn_], 0, 0, 0);               \
        __builtin_amdgcn_s_setprio(0);                                       \
    }

__global__ __launch_bounds__(256, 3) void mlp_pairs_reg(
    const float* __restrict__ x,
    const float* __restrict__ W1, const float* __restrict__ b1,
    const ushort* __restrict__ WF,
    const float* __restrict__ b2, const float* __restrict__ W3,
    const float* __restrict__ b3, float* __restrict__ K)
{
    __shared__ __align__(16) float sa[MD], sc[MD], sb[MD];

    const int t = threadIdx.x;
    const int lane = t & 63;
    const int l15 = lane & 15, l4 = lane >> 4;
    const int wv = t >> 6;

    const float NL2E = -1.4426950408889634f;
    for (int m = t; m < MD; m += 256) {
        const float2 w = reinterpret_cast<const float2*>(W1)[m];
        sa[m] = w.x * NL2E;
        sc[m] = w.y * NL2E;
        sb[m] = b1[m] * NL2E;
    }

    const int pairbase = blockIdx.x * 128 + wv * 32;

    float xia[2], xja[2];
#pragma unroll
    for (int tm = 0; tm < 2; ++tm) {
        const int p = pairbase + tm * 16 + l15;
        if (p < NPAIR) {
            int i, j;
            ptoij(p, i, j);
            xia[tm] = x[i];
            xja[tm] = x[j];
        } else {
            xia[tm] = 0.f;
            xja[tm] = 0.f;
        }
    }

    f32x4 acc[2][8];
#pragma unroll
    for (int a = 0; a < 2; ++a)
#pragma unroll
        for (int b = 0; b < 8; ++b) acc[a][b] = (f32x4){0.f, 0.f, 0.f, 0.f};

    s16x8 bh[8];
    LOADB(0, 0);
    __syncthreads();

    s16x8 ah[2];
    for (int c = 0; c < 16; ++c) {
        SIG_HALF(c, 0);
        MFMA_HALF();
        LOADB(c, 1);
        SIG_HALF(c, 1);
        MFMA_HALF();
        if (c < 15) LOADB(c + 1, 0);
    }

    float w3v[8], b2v[8];
#pragma unroll
    for (int tn = 0; tn < 8; ++tn) {
        const int k = tn * 16 + l15;
        w3v[tn] = W3[k];
        b2v[tn] = b2[k];
    }
    const float b3v = b3[0];
#pragma unroll
    for (int tm = 0; tm < 2; ++tm)
#pragma unroll
        for (int r = 0; r < 4; ++r) {
            float v = 0.f;
#pragma unroll
            for (int tn = 0; tn < 8; ++tn)
                v = fmaf(w3v[tn], fmaxf(acc[tm][tn][r] + b2v[tn], 0.f), v);
            v += __shfl_xor(v, 1, 16);
            v += __shfl_xor(v, 2, 16);
            v += __shfl_xor(v, 4, 16);
            v += __shfl_xor(v, 8, 16);
            if (l15 == 0) {
                const int p = pairbase + tm * 16 + l4 * 4 + r;
                if (p < NPAIR) {
                    int i, j;
                    ptoij(p, i, j);
                    K[i * NN + j] = v + b3v;
                }
            }
        }
}

// ---------- Kernel 2: C = K^T K, symmetric — compute upper tiles, mirror -------
__global__ __launch_bounds__(256) void ktk(const float* __restrict__ K,
                                           float* __restrict__ C)
{
    const int b0 = blockIdx.x * 64;
    const int a0 = blockIdx.y * 64;
    if (b0 < a0) return;             // C symmetric: only tiles with b0 >= a0
    __shared__ float Ka[64][68];
    __shared__ float Kb[64][68];
    const int t  = threadIdx.x;
    const int tb = t & 15;
    const int ta = t >> 4;
    float acc[4][4];
#pragma unroll
    for (int u = 0; u < 4; u++)
#pragma unroll
        for (int v = 0; v < 4; v++) acc[u][v] = 0.f;
    const int kmax = a0 + 64;        // K[k][a]=0 for k>a; a0 <= b0
    for (int k0 = 0; k0 < kmax; k0 += 64) {
#pragma unroll
        for (int q = 0; q < 4; q++) {
            const int f  = t + q * 256;
            const int kk = f >> 4;
            const int c4 = (f & 15) * 4;
            *reinterpret_cast<float4*>(&Ka[kk][c4]) =
                *reinterpret_cast<const float4*>(K + (k0 + kk) * NN + a0 + c4);
            *reinterpret_cast<float4*>(&Kb[kk][c4]) =
                *reinterpret_cast<const float4*>(K + (k0 + kk) * NN + b0 + c4);
        }
        __syncthreads();
#pragma unroll 8
        for (int kk = 0; kk < 64; kk++) {
            const float4 av = *reinterpret_cast<const float4*>(&Ka[kk][ta * 4]);
            const float4 bv = *reinterpret_cast<const float4*>(&Kb[kk][tb * 4]);
            const float a4[4] = {av.x, av.y, av.z, av.w};
            const float b4[4] = {bv.x, bv.y, bv.z, bv.w};
#pragma unroll
            for (int u = 0; u < 4; u++)
#pragma unroll
                for (int v = 0; v < 4; v++)
                    acc[u][v] = fmaf(a4[u], b4[v], acc[u][v]);
        }
        __syncthreads();
    }
#pragma unroll
    for (int u = 0; u < 4; u++) {
        float4 o;
        o.x = acc[u][0]; o.y = acc[u][1]; o.z = acc[u][2]; o.w = acc[u][3];
        *reinterpret_cast<float4*>(C + (a0 + ta * 4 + u) * NN + b0 + tb * 4) = o;
    }
    if (b0 > a0) {                   // mirror tile: C[b][a] = C[a][b], coalesced
#pragma unroll
        for (int v = 0; v < 4; v++) {
            float4 o;
            o.x = acc[0][v]; o.y = acc[1][v]; o.z = acc[2][v]; o.w = acc[3][v];
            *reinterpret_cast<float4*>(C + (b0 + tb * 4 + v) * NN + a0 + ta * 4) = o;
        }
    }
}

extern "C" void kernel_launch(void* const* d_in, const int* in_sizes, int n_in,
                              void* d_out, int out_size, void* d_ws, size_t ws_size,
                              hipStream_t stream)
{
    const float* x  = (const float*)d_in[0];
    const float* W1 = (const float*)d_in[1];
    const float* b1 = (const float*)d_in[2];
    const float* W2 = (const float*)d_in[3];
    const float* b2 = (const float*)d_in[4];
    const float* W3 = (const float*)d_in[5];
    const float* b3 = (const float*)d_in[6];
    float* Kmat = (float*)d_ws;                       // 2,359,296 B
    float* C    = (float*)d_out;

    const size_t kBytes  = (size_t)NN * NN * sizeof(float);
    const size_t wBytes  = 262144;                              // WF
    const size_t eaB     = (size_t)NN * MD * sizeof(float);     // 3 MB
    const size_t ecB     = (size_t)48 * 16384 * sizeof(ushort); // 1.5 MB
    const size_t needTab = kBytes + wBytes + eaB + ecB;         // ~7.2 MB
    const size_t needFB  = kBytes + wBytes;

    hipMemsetAsync(Kmat, 0, kBytes, stream);
    if (ws_size >= needTab) {
        ushort* WF  = (ushort*)((char*)d_ws + kBytes);
        float*  EAg = (float*)((char*)d_ws + kBytes + wBytes);
        ushort* ECF = (ushort*)((char*)d_ws + kBytes + wBytes + eaB);
        prep_all<<<3520, 256, 0, stream>>>(x, W1, b1, W2, WF, ECF, EAg);
        mlp_tab<<<dim3(6, NN), 256, 0, stream>>>(EAg, ECF, WF, b2, W3, b3, Kmat);
    } else if (ws_size >= needFB) {
        ushort* WF = (ushort*)((char*)d_ws + kBytes);
        w2frag<<<64, 256, 0, stream>>>(W2, WF);
        mlp_pairs_reg<<<NPBLK2, 256, 0, stream>>>(x, W1, b1, WF, b2, W3, b3, Kmat);
    }
    ktk<<<dim3(NN / 64, NN / 64), 256, 0, stream>>>(Kmat, C);
}

// Round 20
// 172.924 us; speedup vs baseline: 1.0761x; 1.0196x over previous
//
#include <hip/hip_runtime.h>
#include <hip/hip_bf16.h>

#define NN 768
#define MD 1024
#define NPAIR 295296            // 768*769/2
#define NPBLK2 2307             // fallback kernel grid

typedef __attribute__((ext_vector_type(8))) short s16x8;
typedef __attribute__((ext_vector_type(4))) float f32x4;
typedef __attribute__((ext_vector_type(2))) float f32x2;
typedef __attribute__((ext_vector_type(2))) __bf16 b16x2;

__device__ __forceinline__ ushort bf16_rn(float f) {
    uint u = __builtin_bit_cast(uint, f);
    u += 0x7FFFu + ((u >> 16) & 1u);
    return (ushort)(u >> 16);
}

// inverse triangular index (fallback kernel only)
__device__ __forceinline__ void ptoij(int p, int& io, int& jo) {
    const float disc = (float)(1537 * 1537 - 8 * p);
    int i = (int)((1537.0f - sqrtf(disc)) * 0.5f);
    i = i < 0 ? 0 : (i > 767 ? 767 : i);
    while (i > 0 && p < i * (1537 - i) / 2) --i;
    while (i < 767 && p >= (i + 1) * (1536 - i) / 2) ++i;
    io = i;
    jo = i + (p - i * (1537 - i) / 2);
}

// ---------- one-time prep: WF + ECF (448 blocks, single launch) ----------------
// blocks [0,64):   W2 -> bf16 fragment-major WF
// blocks [64,448): EC factors bf16 fragment-major ECF
__global__ __launch_bounds__(256) void prep_all(
    const float* __restrict__ x,  const float* __restrict__ W1,
    const float* __restrict__ W2,
    ushort* __restrict__ WF, ushort* __restrict__ ECF)
{
    const int b = blockIdx.x;
    const float NL2E = -1.4426950408889634f;
    if (b < 64) {                                    // --- w2frag ---
        const int id = b * 256 + threadIdx.x;        // 0..16383
        const int lane = id & 63;
        const int f = id >> 6;
        const int tn = f & 7;
        const int ks = (f >> 3) & 1;
        const int c  = f >> 4;
        const int k = tn * 16 + (lane & 15);
        const int m = c * 64 + ks * 32 + (lane >> 4) * 8;
        const float4 a = *reinterpret_cast<const float4*>(W2 + k * MD + m);
        const float4 bb = *reinterpret_cast<const float4*>(W2 + k * MD + m + 4);
        const float w[8] = {a.x, a.y, a.z, a.w, bb.x, bb.y, bb.z, bb.w};
        s16x8 h;
#pragma unroll
        for (int e = 0; e < 8; ++e) h[e] = (short)bf16_rn(w[e]);
        *reinterpret_cast<s16x8*>(WF + id * 8) = h;
    } else {                                         // --- ecfprep ---
        const int id = (b - 64) * 256 + threadIdx.x; // 0..98303 (768 j x 128 m8)
        const int j = id >> 7;
        const int m8 = id & 127;
        const float xj = x[j];
        const int mbase = m8 * 8;
        s16x8 h;
#pragma unroll
        for (int e = 0; e < 8; ++e) {
            const float cm = W1[(mbase + e) * 2 + 1];
            h[e] = (short)bf16_rn(__builtin_amdgcn_exp2f(cm * xj * NL2E));
        }
        const int c    = mbase >> 6;
        const int ks   = (mbase >> 5) & 1;
        const int l4   = (mbase & 31) >> 3;
        const int lane = l4 * 16 + (j & 15);
        const int off  = (j >> 4) * 16384 + c * 1024 + ks * 512 + lane * 8;
        *reinterpret_cast<s16x8*>(ECF + off) = h;
    }
}

// ---- table-kernel macros (ambient locals) --------------------------------------
#define LOADB_T(cc, ks)                                                      \
    {                                                                        \
        const ushort* wb_ = WF + (cc) * 8192 + (ks) * 4096 + lane * 8;       \
        _Pragma("unroll")                                                    \
        for (int tn_ = 0; tn_ < 8; ++tn_)                                    \
            bh[tn_] = *reinterpret_cast<const s16x8*>(wb_ + tn_ * 512);      \
    }

#define LOADEC(cc, ks, dst)                                                  \
    {                                                                        \
        const ushort* e_ = ECF + jg0 * 16384 + (cc) * 1024 + (ks) * 512 + lane * 8; \
        dst[0] = *reinterpret_cast<const s16x8*>(e_);                        \
        dst[1] = *reinterpret_cast<const s16x8*>(e_ + 16384);                \
    }

// sigma = rcp(1 + EA*EC): 1 transcendental per value (no exp2 in hot loop)
#define SIG_T(cc, ks_, ec)                                                   \
    {                                                                        \
        const int m0_ = (cc) * 64 + (ks_) * 32 + l4 * 8;                     \
        const f32x4 ea0_ = *reinterpret_cast<const f32x4*>(&EAl[m0_]);       \
        const f32x4 ea1_ = *reinterpret_cast<const f32x4*>(&EAl[m0_ + 4]);   \
        _Pragma("unroll")                                                    \
        for (int tm_ = 0; tm_ < 2; ++tm_) {                                  \
            union { s16x8 v; uint u[4]; } ec_;                               \
            ec_.v = ec[tm_];                                                 \
            union { s16x8 v; uint u[4]; } fr_;                               \
            _Pragma("unroll")                                                \
            for (int h_ = 0; h_ < 4; ++h_) {                                 \
                const uint uu_ = ec_.u[h_];                                  \
                const float el_ = __builtin_bit_cast(float, uu_ << 16);      \
                const float eh_ = __builtin_bit_cast(float, uu_ & 0xFFFF0000u); \
                const float ga_ = (h_ < 2) ? ea0_[2 * h_] : ea1_[2 * h_ - 4];     \
                const float gb_ = (h_ < 2) ? ea0_[2 * h_ + 1] : ea1_[2 * h_ - 3]; \
                const float t0_ = fmaf(el_, ga_, 1.0f);                      \
                const float t1_ = fmaf(eh_, gb_, 1.0f);                      \
                b16x2 p_;                                                    \
                p_.x = (__bf16)__builtin_amdgcn_rcpf(t0_);                   \
                p_.y = (__bf16)__builtin_amdgcn_rcpf(t1_);                   \
                fr_.u[h_] = __builtin_bit_cast(uint, p_);                    \
            }                                                                \
            ah[tm_] = fr_.v;                                                 \
        }                                                                    \
    }

#define MFMA_T()                                                             \
    {                                                                        \
        __builtin_amdgcn_s_setprio(1);                                       \
        _Pragma("unroll")                                                    \
        for (int tm_ = 0; tm_ < 2; ++tm_)                                    \
            _Pragma("unroll")                                                \
            for (int tn_ = 0; tn_ < 8; ++tn_)                                \
                acc[tm_][tn_] = __builtin_amdgcn_mfma_f32_16x16x32_bf16(     \
                    ah[tm_], bh[tn_], acc[tm_][tn_], 0, 0, 0);               \
        __builtin_amdgcn_s_setprio(0);                                       \
    }

// ---------- main: (i, 64 j) blocks, 2 waves x (32 j x 128 k), in-kernel EA -----
// proven mlp_tab inner loop; 8.2% waste vs 16.5% at 128-j blocks
__global__ __launch_bounds__(128, 3) void mlp_tab64(
    const float* __restrict__ x,
    const float* __restrict__ W1, const float* __restrict__ b1,
    const ushort* __restrict__ ECF, const ushort* __restrict__ WF,
    const float* __restrict__ b2, const float* __restrict__ W3,
    const float* __restrict__ b3, float* __restrict__ K)
{
    const int i  = blockIdx.y;
    const int j0 = blockIdx.x * 64;
    if (j0 + 63 < i) return;                  // fully below diagonal

    __shared__ __align__(16) float EAl[MD];   // 4 KB

    const int t = threadIdx.x;
    const int lane = t & 63, wv = t >> 6;     // 2 waves
    const int l15 = lane & 15, l4 = lane >> 4;

    const int jw  = j0 + wv * 32;             // wave's 32 j rows
    const int jg0 = jw >> 4;                  // first of two 16-j fragment groups

    // prologue: compute EA row in-kernel (8 exp2/thread) — no global EA table
    const float NL2E = -1.4426950408889634f;
    const float xi = x[i];
    for (int m = t; m < MD; m += 128) {
        const float2 w = reinterpret_cast<const float2*>(W1)[m];
        EAl[m] = __builtin_amdgcn_exp2f(fmaf(w.x, xi, b1[m]) * NL2E);
    }

    f32x4 acc[2][8];
#pragma unroll
    for (int a = 0; a < 2; ++a)
#pragma unroll
        for (int b = 0; b < 8; ++b) acc[a][b] = (f32x4){0.f, 0.f, 0.f, 0.f};

    s16x8 bh[8], ecA[2], ecB[2], ah[2];
    LOADB_T(0, 0);
    LOADEC(0, 0, ecA);
    __syncthreads();                 // EAl resident (the ONLY barrier)

    for (int c = 0; c < 16; ++c) {
        LOADEC(c, 1, ecB);           // flies over SIG0+MFMA0
        SIG_T(c, 0, ecA);            // consumes ecA; covers in-flight bh ks0
        MFMA_T();                    // consumes bh = ks0
        LOADB_T(c, 1);               // refill bh with ks1 frags
        if (c < 15) LOADEC(c + 1, 0, ecA);   // flies over SIG1+MFMA1
        SIG_T(c, 1, ecB);
        MFMA_T();                    // consumes bh = ks1
        if (c < 15) LOADB_T(c + 1, 0);
    }

    // epilogue: v = sum_k W3[k]*relu(h2 + b2[k]) + b3; reduce over 16 lanes (k)
    float w3v[8], b2v[8];
#pragma unroll
    for (int tn = 0; tn < 8; ++tn) {
        const int k = tn * 16 + l15;
        w3v[tn] = W3[k];
        b2v[tn] = b2[k];
    }
    const float b3v = b3[0];
#pragma unroll
    for (int tm = 0; tm < 2; ++tm)
#pragma unroll
        for (int r = 0; r < 4; ++r) {
            float v = 0.f;
#pragma unroll
            for (int tn = 0; tn < 8; ++tn)
                v = fmaf(w3v[tn], fmaxf(acc[tm][tn][r] + b2v[tn], 0.f), v);
            v += __shfl_xor(v, 1, 16);
            v += __shfl_xor(v, 2, 16);
            v += __shfl_xor(v, 4, 16);
            v += __shfl_xor(v, 8, 16);
            if (l15 == 0) {
                const int j = jw + tm * 16 + l4 * 4 + r;
                if (j >= i) K[i * NN + j] = v + b3v;
            }
        }
}

// ---------- fallback (R16 proven): pair-flattened, exp2-in-loop, zero barriers -
__global__ __launch_bounds__(256) void w2frag(const float* __restrict__ W2,
                                              ushort* __restrict__ WF)
{
    const int id = blockIdx.x * 256 + threadIdx.x;
    const int lane = id & 63;
    const int f = id >> 6;
    const int tn = f & 7;
    const int ks = (f >> 3) & 1;
    const int c  = f >> 4;
    const int k = tn * 16 + (lane & 15);
    const int m = c * 64 + ks * 32 + (lane >> 4) * 8;
    const float4 a = *reinterpret_cast<const float4*>(W2 + k * MD + m);
    const float4 b = *reinterpret_cast<const float4*>(W2 + k * MD + m + 4);
    const float w[8] = {a.x, a.y, a.z, a.w, b.x, b.y, b.z, b.w};
    s16x8 h;
#pragma unroll
    for (int e = 0; e < 8; ++e) h[e] = (short)bf16_rn(w[e]);
    *reinterpret_cast<s16x8*>(WF + id * 8) = h;
}

#define LOADB(cc, ks)                                                        \
    {                                                                        \
        const ushort* wb_ = WF + (cc) * 8192 + (ks) * 4096 + lane * 8;       \
        _Pragma("unroll")                                                    \
        for (int tn_ = 0; tn_ < 8; ++tn_)                                    \
            bh[tn_] = *reinterpret_cast<const s16x8*>(wb_ + tn_ * 512);      \
    }

#define SIG_HALF(cc, ks_)                                                    \
    {                                                                        \
        const int m0_ = (cc) * 64 + (ks_) * 32 + l4 * 8;                     \
        const f32x4 a0_ = *reinterpret_cast<const f32x4*>(&sa[m0_]);         \
        const f32x4 a1_ = *reinterpret_cast<const f32x4*>(&sa[m0_ + 4]);     \
        const f32x4 c0_ = *reinterpret_cast<const f32x4*>(&sc[m0_]);         \
        const f32x4 c1_ = *reinterpret_cast<const f32x4*>(&sc[m0_ + 4]);     \
        const f32x4 b0_ = *reinterpret_cast<const f32x4*>(&sb[m0_]);         \
        const f32x4 b1_ = *reinterpret_cast<const f32x4*>(&sb[m0_ + 4]);     \
        _Pragma("unroll")                                                    \
        for (int tm_ = 0; tm_ < 2; ++tm_) {                                  \
            const f32x2 xi2_ = (f32x2){xia[tm_], xia[tm_]};                  \
            const f32x2 xj2_ = (f32x2){xja[tm_], xja[tm_]};                  \
            const f32x2 one2_ = (f32x2){1.f, 1.f};                           \
            union { s16x8 v; uint u[4]; } fr_;                               \
            _Pragma("unroll")                                                \
            for (int h_ = 0; h_ < 4; ++h_) {                                 \
                f32x2 av_, cv_, bv_;                                         \
                if (h_ < 2) {                                                \
                    av_ = (f32x2){a0_[2 * h_], a0_[2 * h_ + 1]};             \
                    cv_ = (f32x2){c0_[2 * h_], c0_[2 * h_ + 1]};             \
                    bv_ = (f32x2){b0_[2 * h_], b0_[2 * h_ + 1]};             \
                } else {                                                     \
                    av_ = (f32x2){a1_[2 * h_ - 4], a1_[2 * h_ - 3]};         \
                    cv_ = (f32x2){c1_[2 * h_ - 4], c1_[2 * h_ - 3]};         \
                    bv_ = (f32x2){b1_[2 * h_ - 4], b1_[2 * h_ - 3]};         \
                }                                                            \
                const f32x2 u2_ = __builtin_elementwise_fma(                 \
                    xi2_, av_, __builtin_elementwise_fma(xj2_, cv_, bv_));   \
                f32x2 e2_;                                                   \
                e2_[0] = __builtin_amdgcn_exp2f(u2_[0]);                     \
                e2_[1] = __builtin_amdgcn_exp2f(u2_[1]);                     \
                const f32x2 t2_ = e2_ + one2_;                               \
                b16x2 p_;                                                    \
                p_.x = (__bf16)__builtin_amdgcn_rcpf(t2_[0]);                \
                p_.y = (__bf16)__builtin_amdgcn_rcpf(t2_[1]);                \
                fr_.u[h_] = __builtin_bit_cast(uint, p_);                    \
            }                                                                \
            ah[tm_] = fr_.v;                                                 \
        }                                                                    \
    }

#define MFMA_HALF()                                                          \
    {                                                                        \
        __builtin_amdgcn_s_setprio(1);                                       \
        _Pragma("unroll")                                                    \
        for (int tm_ = 0; tm_ < 2; ++tm_)                                    \
            _Pragma("unroll")                                                \
            for (int tn_ = 0; tn_ < 8; ++tn_)                                \
                acc[tm_][tn_] = __builtin_amdgcn_mfma_f32_16x16x32_bf16(     \
                    ah[tm_], bh[tn_], acc[tm_][tn_], 0, 0, 0);               \
        __builtin_amdgcn_s_setprio(0);                                       \
    }

__global__ __launch_bounds__(256, 3) void mlp_pairs_reg(
    const float* __restrict__ x,
    const float* __restrict__ W1, const float* __restrict__ b1,
    const ushort* __restrict__ WF,
    const float* __restrict__ b2, const float* __restrict__ W3,
    const float* __restrict__ b3, float* __restrict__ K)
{
    __shared__ __align__(16) float sa[MD], sc[MD], sb[MD];

    const int t = threadIdx.x;
    const int lane = t & 63;
    const int l15 = lane & 15, l4 = lane >> 4;
    const int wv = t >> 6;

    const float NL2E = -1.4426950408889634f;
    for (int m = t; m < MD; m += 256) {
        const float2 w = reinterpret_cast<const float2*>(W1)[m];
        sa[m] = w.x * NL2E;
        sc[m] = w.y * NL2E;
        sb[m] = b1[m] * NL2E;
    }

    const int pairbase = blockIdx.x * 128 + wv * 32;

    float xia[2], xja[2];
#pragma unroll
    for (int tm = 0; tm < 2; ++tm) {
        const int p = pairbase + tm * 16 + l15;
        if (p < NPAIR) {
            int i, j;
            ptoij(p, i, j);
            xia[tm] = x[i];
            xja[tm] = x[j];
        } else {
            xia[tm] = 0.f;
            xja[tm] = 0.f;
        }
    }

    f32x4 acc[2][8];
#pragma unroll
    for (int a = 0; a < 2; ++a)
#pragma unroll
        for (int b = 0; b < 8; ++b) acc[a][b] = (f32x4){0.f, 0.f, 0.f, 0.f};

    s16x8 bh[8];
    LOADB(0, 0);
    __syncthreads();

    s16x8 ah[2];
    for (int c = 0; c < 16; ++c) {
        SIG_HALF(c, 0);
        MFMA_HALF();
        LOADB(c, 1);
        SIG_HALF(c, 1);
        MFMA_HALF();
        if (c < 15) LOADB(c + 1, 0);
    }

    float w3v[8], b2v[8];
#pragma unroll
    for (int tn = 0; tn < 8; ++tn) {
        const int k = tn * 16 + l15;
        w3v[tn] = W3[k];
        b2v[tn] = b2[k];
    }
    const float b3v = b3[0];
#pragma unroll
    for (int tm = 0; tm < 2; ++tm)
#pragma unroll
        for (int r = 0; r < 4; ++r) {
            float v = 0.f;
#pragma unroll
            for (int tn = 0; tn < 8; ++tn)
                v = fmaf(w3v[tn], fmaxf(acc[tm][tn][r] + b2v[tn], 0.f), v);
            v += __shfl_xor(v, 1, 16);
            v += __shfl_xor(v, 2, 16);
            v += __shfl_xor(v, 4, 16);
            v += __shfl_xor(v, 8, 16);
            if (l15 == 0) {
                const int p = pairbase + tm * 16 + l4 * 4 + r;
                if (p < NPAIR) {
                    int i, j;
                    ptoij(p, i, j);
                    K[i * NN + j] = v + b3v;
                }
            }
        }
}

// ---------- Kernel 2: C = K^T K, symmetric — compute upper tiles, mirror -------
__global__ __launch_bounds__(256) void ktk(const float* __restrict__ K,
                                           float* __restrict__ C)
{
    const int b0 = blockIdx.x * 64;
    const int a0 = blockIdx.y * 64;
    if (b0 < a0) return;             // C symmetric: only tiles with b0 >= a0
    __shared__ float Ka[64][68];
    __shared__ float Kb[64][68];
    const int t  = threadIdx.x;
    const int tb = t & 15;
    const int ta = t >> 4;
    float acc[4][4];
#pragma unroll
    for (int u = 0; u < 4; u++)
#pragma unroll
        for (int v = 0; v < 4; v++) acc[u][v] = 0.f;
    const int kmax = a0 + 64;        // K[k][a]=0 for k>a; a0 <= b0
    for (int k0 = 0; k0 < kmax; k0 += 64) {
#pragma unroll
        for (int q = 0; q < 4; q++) {
            const int f  = t + q * 256;
            const int kk = f >> 4;
            const int c4 = (f & 15) * 4;
            *reinterpret_cast<float4*>(&Ka[kk][c4]) =
                *reinterpret_cast<const float4*>(K + (k0 + kk) * NN + a0 + c4);
            *reinterpret_cast<float4*>(&Kb[kk][c4]) =
                *reinterpret_cast<const float4*>(K + (k0 + kk) * NN + b0 + c4);
        }
        __syncthreads();
#pragma unroll 8
        for (int kk = 0; kk < 64; kk++) {
            const float4 av = *reinterpret_cast<const float4*>(&Ka[kk][ta * 4]);
            const float4 bv = *reinterpret_cast<const float4*>(&Kb[kk][tb * 4]);
            const float a4[4] = {av.x, av.y, av.z, av.w};
            const float b4[4] = {bv.x, bv.y, bv.z, bv.w};
#pragma unroll
            for (int u = 0; u < 4; u++)
#pragma unroll
                for (int v = 0; v < 4; v++)
                    acc[u][v] = fmaf(a4[u], b4[v], acc[u][v]);
        }
        __syncthreads();
    }
#pragma unroll
    for (int u = 0; u < 4; u++) {
        float4 o;
        o.x = acc[u][0]; o.y = acc[u][1]; o.z = acc[u][2]; o.w = acc[u][3];
        *reinterpret_cast<float4*>(C + (a0 + ta * 4 + u) * NN + b0 + tb * 4) = o;
    }
    if (b0 > a0) {                   // mirror tile: C[b][a] = C[a][b], coalesced
#pragma unroll
        for (int v = 0; v < 4; v++) {
            float4 o;
            o.x = acc[0][v]; o.y = acc[1][v]; o.z = acc[2][v]; o.w = acc[3][v];
            *reinterpret_cast<float4*>(C + (b0 + tb * 4 + v) * NN + a0 + ta * 4) = o;
        }
    }
}

extern "C" void kernel_launch(void* const* d_in, const int* in_sizes, int n_in,
                              void* d_out, int out_size, void* d_ws, size_t ws_size,
                              hipStream_t stream)
{
    const float* x  = (const float*)d_in[0];
    const float* W1 = (const float*)d_in[1];
    const float* b1 = (const float*)d_in[2];
    const float* W2 = (const float*)d_in[3];
    const float* b2 = (const float*)d_in[4];
    const float* W3 = (const float*)d_in[5];
    const float* b3 = (const float*)d_in[6];
    float* Kmat = (float*)d_ws;                       // 2,359,296 B
    float* C    = (float*)d_out;

    const size_t kBytes  = (size_t)NN * NN * sizeof(float);
    const size_t wBytes  = 262144;                              // WF
    const size_t ecB     = (size_t)48 * 16384 * sizeof(ushort); // 1.5 MB
    const size_t needTab = kBytes + wBytes + ecB;               // ~4.1 MB
    const size_t needFB  = kBytes + wBytes;

    hipMemsetAsync(Kmat, 0, kBytes, stream);
    if (ws_size >= needTab) {
        ushort* WF  = (ushort*)((char*)d_ws + kBytes);
        ushort* ECF = (ushort*)((char*)d_ws + kBytes + wBytes);
        prep_all<<<448, 256, 0, stream>>>(x, W1, W2, WF, ECF);
        mlp_tab64<<<dim3(12, NN), 128, 0, stream>>>(x, W1, b1, ECF, WF,
                                                    b2, W3, b3, Kmat);
    } else if (ws_size >= needFB) {
        ushort* WF = (ushort*)((char*)d_ws + kBytes);
        w2frag<<<64, 256, 0, stream>>>(W2, WF);
        mlp_pairs_reg<<<NPBLK2, 256, 0, stream>>>(x, W1, b1, WF, b2, W3, b3, Kmat);
    }
    ktk<<<dim3(NN / 64, NN / 64), 256, 0, stream>>>(Kmat, C);
}

// Round 21
// 170.819 us; speedup vs baseline: 1.0893x; 1.0123x over previous
//
#include <hip/hip_runtime.h>
#include <hip/hip_bf16.h>

#define NN 768
#define MD 1024
#define NPAIR 295296            // 768*769/2
#define NPBLK2 2307             // fallback kernel grid

typedef __attribute__((ext_vector_type(8))) short s16x8;
typedef __attribute__((ext_vector_type(4))) float f32x4;
typedef __attribute__((ext_vector_type(2))) float f32x2;
typedef __attribute__((ext_vector_type(2))) __bf16 b16x2;

__device__ __forceinline__ ushort bf16_rn(float f) {
    uint u = __builtin_bit_cast(uint, f);
    u += 0x7FFFu + ((u >> 16) & 1u);
    return (ushort)(u >> 16);
}

// inverse triangular index (fallback kernel only)
__device__ __forceinline__ void ptoij(int p, int& io, int& jo) {
    const float disc = (float)(1537 * 1537 - 8 * p);
    int i = (int)((1537.0f - sqrtf(disc)) * 0.5f);
    i = i < 0 ? 0 : (i > 767 ? 767 : i);
    while (i > 0 && p < i * (1537 - i) / 2) --i;
    while (i < 767 && p >= (i + 1) * (1536 - i) / 2) ++i;
    io = i;
    jo = i + (p - i * (1537 - i) / 2);
}

// ---------- fused one-time prep: WF + ECF + zero-K (single launch) -------------
// blocks [0,64):    W2 -> bf16 fragment-major WF
// blocks [64,448):  EC factors bf16 fragment-major ECF
// blocks [448,1024): zero Kmat (576 blocks x 256 thr x 16B = 2,359,296 B)
__global__ __launch_bounds__(256) void prep_all(
    const float* __restrict__ x,  const float* __restrict__ W1,
    const float* __restrict__ W2,
    ushort* __restrict__ WF, ushort* __restrict__ ECF,
    float* __restrict__ Kz)
{
    const int b = blockIdx.x;
    const float NL2E = -1.4426950408889634f;
    if (b < 64) {                                    // --- w2frag ---
        const int id = b * 256 + threadIdx.x;        // 0..16383
        const int lane = id & 63;
        const int f = id >> 6;
        const int tn = f & 7;
        const int ks = (f >> 3) & 1;
        const int c  = f >> 4;
        const int k = tn * 16 + (lane & 15);
        const int m = c * 64 + ks * 32 + (lane >> 4) * 8;
        const float4 a = *reinterpret_cast<const float4*>(W2 + k * MD + m);
        const float4 bb = *reinterpret_cast<const float4*>(W2 + k * MD + m + 4);
        const float w[8] = {a.x, a.y, a.z, a.w, bb.x, bb.y, bb.z, bb.w};
        s16x8 h;
#pragma unroll
        for (int e = 0; e < 8; ++e) h[e] = (short)bf16_rn(w[e]);
        *reinterpret_cast<s16x8*>(WF + id * 8) = h;
    } else if (b < 448) {                            // --- ecfprep ---
        const int id = (b - 64) * 256 + threadIdx.x; // 0..98303 (768 j x 128 m8)
        const int j = id >> 7;
        const int m8 = id & 127;
        const float xj = x[j];
        const int mbase = m8 * 8;
        s16x8 h;
#pragma unroll
        for (int e = 0; e < 8; ++e) {
            const float cm = W1[(mbase + e) * 2 + 1];
            h[e] = (short)bf16_rn(__builtin_amdgcn_exp2f(cm * xj * NL2E));
        }
        const int c    = mbase >> 6;
        const int ks   = (mbase >> 5) & 1;
        const int l4   = (mbase & 31) >> 3;
        const int lane = l4 * 16 + (j & 15);
        const int off  = (j >> 4) * 16384 + c * 1024 + ks * 512 + lane * 8;
        *reinterpret_cast<s16x8*>(ECF + off) = h;
    } else {                                         // --- zero K ---
        const int id = (b - 448) * 256 + threadIdx.x;
        *reinterpret_cast<f32x4*>(Kz + id * 4) = (f32x4){0.f, 0.f, 0.f, 0.f};
    }
}

// ---- table-kernel macros (ambient locals) --------------------------------------
#define LOADB_T(cc, ks)                                                      \
    {                                                                        \
        const ushort* wb_ = WF + (cc) * 8192 + (ks) * 4096 + lane * 8;       \
        _Pragma("unroll")                                                    \
        for (int tn_ = 0; tn_ < 8; ++tn_)                                    \
            bh[tn_] = *reinterpret_cast<const s16x8*>(wb_ + tn_ * 512);      \
    }

#define LOADEC(cc, ks, dst)                                                  \
    {                                                                        \
        const ushort* e_ = ECF + jg0 * 16384 + (cc) * 1024 + (ks) * 512 + lane * 8; \
        dst[0] = *reinterpret_cast<const s16x8*>(e_);                        \
        dst[1] = *reinterpret_cast<const s16x8*>(e_ + 16384);                \
    }

// sigma = rcp(1 + EA*EC): 1 transcendental per value (no exp2 in hot loop)
#define SIG_T(cc, ks_, ec)                                                   \
    {                                                                        \
        const int m0_ = (cc) * 64 + (ks_) * 32 + l4 * 8;                     \
        const f32x4 ea0_ = *reinterpret_cast<const f32x4*>(&EAl[m0_]);       \
        const f32x4 ea1_ = *reinterpret_cast<const f32x4*>(&EAl[m0_ + 4]);   \
        _Pragma("unroll")                                                    \
        for (int tm_ = 0; tm_ < 2; ++tm_) {                                  \
            union { s16x8 v; uint u[4]; } ec_;                               \
            ec_.v = ec[tm_];                                                 \
            union { s16x8 v; uint u[4]; } fr_;                               \
            _Pragma("unroll")                                                \
            for (int h_ = 0; h_ < 4; ++h_) {                                 \
                const uint uu_ = ec_.u[h_];                                  \
                const float el_ = __builtin_bit_cast(float, uu_ << 16);      \
                const float eh_ = __builtin_bit_cast(float, uu_ & 0xFFFF0000u); \
                const float ga_ = (h_ < 2) ? ea0_[2 * h_] : ea1_[2 * h_ - 4];     \
                const float gb_ = (h_ < 2) ? ea0_[2 * h_ + 1] : ea1_[2 * h_ - 3]; \
                const float t0_ = fmaf(el_, ga_, 1.0f);                      \
                const float t1_ = fmaf(eh_, gb_, 1.0f);                      \
                b16x2 p_;                                                    \
                p_.x = (__bf16)__builtin_amdgcn_rcpf(t0_);                   \
                p_.y = (__bf16)__builtin_amdgcn_rcpf(t1_);                   \
                fr_.u[h_] = __builtin_bit_cast(uint, p_);                    \
            }                                                                \
            ah[tm_] = fr_.v;                                                 \
        }                                                                    \
    }

#define MFMA_T()                                                             \
    {                                                                        \
        __builtin_amdgcn_s_setprio(1);                                       \
        _Pragma("unroll")                                                    \
        for (int tm_ = 0; tm_ < 2; ++tm_)                                    \
            _Pragma("unroll")                                                \
            for (int tn_ = 0; tn_ < 8; ++tn_)                                \
                acc[tm_][tn_] = __builtin_amdgcn_mfma_f32_16x16x32_bf16(     \
                    ah[tm_], bh[tn_], acc[tm_][tn_], 0, 0, 0);               \
        __builtin_amdgcn_s_setprio(0);                                       \
    }

// ---------- main (R17 hot loop): row-block (i,128 j), in-kernel EA -------------
__global__ __launch_bounds__(256, 3) void mlp_tab(
    const float* __restrict__ x,
    const float* __restrict__ W1, const float* __restrict__ b1,
    const ushort* __restrict__ ECF, const ushort* __restrict__ WF,
    const float* __restrict__ b2, const float* __restrict__ W3,
    const float* __restrict__ b3, float* __restrict__ K)
{
    const int i  = blockIdx.y;
    const int j0 = blockIdx.x * 128;
    if (j0 + 127 < i) return;                 // fully below diagonal

    __shared__ __align__(16) float EAl[MD];   // 4 KB only

    const int t = threadIdx.x;
    const int lane = t & 63, wv = t >> 6;
    const int l15 = lane & 15, l4 = lane >> 4;

    const int jw  = j0 + wv * 32;             // wave's 32 j rows
    const int jg0 = jw >> 4;                  // first of two 16-j fragment groups

    // prologue: compute EA row in-kernel (4 exp2/thread) — no global EA table
    const float NL2E = -1.4426950408889634f;
    const float xi = x[i];
    for (int m = t; m < MD; m += 256) {
        const float2 w = reinterpret_cast<const float2*>(W1)[m];
        EAl[m] = __builtin_amdgcn_exp2f(fmaf(w.x, xi, b1[m]) * NL2E);
    }

    f32x4 acc[2][8];
#pragma unroll
    for (int a = 0; a < 2; ++a)
#pragma unroll
        for (int b = 0; b < 8; ++b) acc[a][b] = (f32x4){0.f, 0.f, 0.f, 0.f};

    s16x8 bh[8], ecA[2], ecB[2], ah[2];
    LOADB_T(0, 0);
    LOADEC(0, 0, ecA);
    __syncthreads();                 // EAl resident (the ONLY barrier)

    for (int c = 0; c < 16; ++c) {
        LOADEC(c, 1, ecB);           // flies over SIG0+MFMA0
        SIG_T(c, 0, ecA);            // consumes ecA; covers in-flight bh ks0
        MFMA_T();                    // consumes bh = ks0
        LOADB_T(c, 1);               // refill bh with ks1 frags
        if (c < 15) LOADEC(c + 1, 0, ecA);   // flies over SIG1+MFMA1
        SIG_T(c, 1, ecB);
        MFMA_T();                    // consumes bh = ks1
        if (c < 15) LOADB_T(c + 1, 0);
    }

    // epilogue: v = sum_k W3[k]*relu(h2 + b2[k]) + b3; reduce over 16 lanes (k)
    float w3v[8], b2v[8];
#pragma unroll
    for (int tn = 0; tn < 8; ++tn) {
        const int k = tn * 16 + l15;
        w3v[tn] = W3[k];
        b2v[tn] = b2[k];
    }
    const float b3v = b3[0];
#pragma unroll
    for (int tm = 0; tm < 2; ++tm)
#pragma unroll
        for (int r = 0; r < 4; ++r) {
            float v = 0.f;
#pragma unroll
            for (int tn = 0; tn < 8; ++tn)
                v = fmaf(w3v[tn], fmaxf(acc[tm][tn][r] + b2v[tn], 0.f), v);
            v += __shfl_xor(v, 1, 16);
            v += __shfl_xor(v, 2, 16);
            v += __shfl_xor(v, 4, 16);
            v += __shfl_xor(v, 8, 16);
            if (l15 == 0) {
                const int j = jw + tm * 16 + l4 * 4 + r;
                if (j >= i) K[i * NN + j] = v + b3v;
            }
        }
}

// ---------- fallback (R16 proven): pair-flattened, exp2-in-loop, zero barriers -
__global__ __launch_bounds__(256) void w2frag(const float* __restrict__ W2,
                                              ushort* __restrict__ WF)
{
    const int id = blockIdx.x * 256 + threadIdx.x;
    const int lane = id & 63;
    const int f = id >> 6;
    const int tn = f & 7;
    const int ks = (f >> 3) & 1;
    const int c  = f >> 4;
    const int k = tn * 16 + (lane & 15);
    const int m = c * 64 + ks * 32 + (lane >> 4) * 8;
    const float4 a = *reinterpret_cast<const float4*>(W2 + k * MD + m);
    const float4 b = *reinterpret_cast<const float4*>(W2 + k * MD + m + 4);
    const float w[8] = {a.x, a.y, a.z, a.w, b.x, b.y, b.z, b.w};
    s16x8 h;
#pragma unroll
    for (int e = 0; e < 8; ++e) h[e] = (short)bf16_rn(w[e]);
    *reinterpret_cast<s16x8*>(WF + id * 8) = h;
}

#define LOADB(cc, ks)                                                        \
    {                                                                        \
        const ushort* wb_ = WF + (cc) * 8192 + (ks) * 4096 + lane * 8;       \
        _Pragma("unroll")                                                    \
        for (int tn_ = 0; tn_ < 8; ++tn_)                                    \
            bh[tn_] = *reinterpret_cast<const s16x8*>(wb_ + tn_ * 512);      \
    }

#define SIG_HALF(cc, ks_)                                                    \
    {                                                                        \
        const int m0_ = (cc) * 64 + (ks_) * 32 + l4 * 8;                     \
        const f32x4 a0_ = *reinterpret_cast<const f32x4*>(&sa[m0_]);         \
        const f32x4 a1_ = *reinterpret_cast<const f32x4*>(&sa[m0_ + 4]);     \
        const f32x4 c0_ = *reinterpret_cast<const f32x4*>(&sc[m0_]);         \
        const f32x4 c1_ = *reinterpret_cast<const f32x4*>(&sc[m0_ + 4]);     \
        const f32x4 b0_ = *reinterpret_cast<const f32x4*>(&sb[m0_]);         \
        const f32x4 b1_ = *reinterpret_cast<const f32x4*>(&sb[m0_ + 4]);     \
        _Pragma("unroll")                                                    \
        for (int tm_ = 0; tm_ < 2; ++tm_) {                                  \
            const f32x2 xi2_ = (f32x2){xia[tm_], xia[tm_]};                  \
            const f32x2 xj2_ = (f32x2){xja[tm_], xja[tm_]};                  \
            const f32x2 one2_ = (f32x2){1.f, 1.f};                           \
            union { s16x8 v; uint u[4]; } fr_;                               \
            _Pragma("unroll")                                                \
            for (int h_ = 0; h_ < 4; ++h_) {                                 \
                f32x2 av_, cv_, bv_;                                         \
                if (h_ < 2) {                                                \
                    av_ = (f32x2){a0_[2 * h_], a0_[2 * h_ + 1]};             \
                    cv_ = (f32x2){c0_[2 * h_], c0_[2 * h_ + 1]};             \
                    bv_ = (f32x2){b0_[2 * h_], b0_[2 * h_ + 1]};             \
                } else {                                                     \
                    av_ = (f32x2){a1_[2 * h_ - 4], a1_[2 * h_ - 3]};         \
                    cv_ = (f32x2){c1_[2 * h_ - 4], c1_[2 * h_ - 3]};         \
                    bv_ = (f32x2){b1_[2 * h_ - 4], b1_[2 * h_ - 3]};         \
                }                                                            \
                const f32x2 u2_ = __builtin_elementwise_fma(                 \
                    xi2_, av_, __builtin_elementwise_fma(xj2_, cv_, bv_));   \
                f32x2 e2_;                                                   \
                e2_[0] = __builtin_amdgcn_exp2f(u2_[0]);                     \
                e2_[1] = __builtin_amdgcn_exp2f(u2_[1]);                     \
                const f32x2 t2_ = e2_ + one2_;                               \
                b16x2 p_;                                                    \
                p_.x = (__bf16)__builtin_amdgcn_rcpf(t2_[0]);                \
                p_.y = (__bf16)__builtin_amdgcn_rcpf(t2_[1]);                \
                fr_.u[h_] = __builtin_bit_cast(uint, p_);                    \
            }                                                                \
            ah[tm_] = fr_.v;                                                 \
        }                                                                    \
    }

#define MFMA_HALF()                                                          \
    {                                                                        \
        __builtin_amdgcn_s_setprio(1);                                       \
        _Pragma("unroll")                                                    \
        for (int tm_ = 0; tm_ < 2; ++tm_)                                    \
            _Pragma("unroll")                                                \
            for (int tn_ = 0; tn_ < 8; ++tn_)                                \
                acc[tm_][tn_] = __builtin_amdgcn_mfma_f32_16x16x32_bf16(     \
                    ah[tm_], bh[tn_], acc[tm_][tn_], 0, 0, 0);               \
        __builtin_amdgcn_s_setprio(0);                                       \
    }

__global__ __launch_bounds__(256, 3) void mlp_pairs_reg(
    const float* __restrict__ x,
    const float* __restrict__ W1, const float* __restrict__ b1,
    const ushort* __restrict__ WF,
    const float* __restrict__ b2, const float* __restrict__ W3,
    const float* __restrict__ b3, float* __restrict__ K)
{
    __shared__ __align__(16) float sa[MD], sc[MD], sb[MD];

    const int t = threadIdx.x;
    const int lane = t & 63;
    const int l15 = lane & 15, l4 = lane >> 4;
    const int wv = t >> 6;

    const float NL2E = -1.4426950408889634f;
    for (int m = t; m < MD; m += 256) {
        const float2 w = reinterpret_cast<const float2*>(W1)[m];
        sa[m] = w.x * NL2E;
        sc[m] = w.y * NL2E;
        sb[m] = b1[m] * NL2E;
    }

    const int pairbase = blockIdx.x * 128 + wv * 32;

    float xia[2], xja[2];
#pragma unroll
    for (int tm = 0; tm < 2; ++tm) {
        const int p = pairbase + tm * 16 + l15;
        if (p < NPAIR) {
            int i, j;
            ptoij(p, i, j);
            xia[tm] = x[i];
            xja[tm] = x[j];
        } else {
            xia[tm] = 0.f;
            xja[tm] = 0.f;
        }
    }

    f32x4 acc[2][8];
#pragma unroll
    for (int a = 0; a < 2; ++a)
#pragma unroll
        for (int b = 0; b < 8; ++b) acc[a][b] = (f32x4){0.f, 0.f, 0.f, 0.f};

    s16x8 bh[8];
    LOADB(0, 0);
    __syncthreads();

    s16x8 ah[2];
    for (int c = 0; c < 16; ++c) {
        SIG_HALF(c, 0);
        MFMA_HALF();
        LOADB(c, 1);
        SIG_HALF(c, 1);
        MFMA_HALF();
        if (c < 15) LOADB(c + 1, 0);
    }

    float w3v[8], b2v[8];
#pragma unroll
    for (int tn = 0; tn < 8; ++tn) {
        const int k = tn * 16 + l15;
        w3v[tn] = W3[k];
        b2v[tn] = b2[k];
    }
    const float b3v = b3[0];
#pragma unroll
    for (int tm = 0; tm < 2; ++tm)
#pragma unroll
        for (int r = 0; r < 4; ++r) {
            float v = 0.f;
#pragma unroll
            for (int tn = 0; tn < 8; ++tn)
                v = fmaf(w3v[tn], fmaxf(acc[tm][tn][r] + b2v[tn], 0.f), v);
            v += __shfl_xor(v, 1, 16);
            v += __shfl_xor(v, 2, 16);
            v += __shfl_xor(v, 4, 16);
            v += __shfl_xor(v, 8, 16);
            if (l15 == 0) {
                const int p = pairbase + tm * 16 + l4 * 4 + r;
                if (p < NPAIR) {
                    int i, j;
                    ptoij(p, i, j);
                    K[i * NN + j] = v + b3v;
                }
            }
        }
}

// ---------- Kernel 2: C = K^T K, symmetric — compute upper tiles, mirror -------
__global__ __launch_bounds__(256) void ktk(const float* __restrict__ K,
                                           float* __restrict__ C)
{
    const int b0 = blockIdx.x * 64;
    const int a0 = blockIdx.y * 64;
    if (b0 < a0) return;             // C symmetric: only tiles with b0 >= a0
    __shared__ float Ka[64][68];
    __shared__ float Kb[64][68];
    const int t  = threadIdx.x;
    const int tb = t & 15;
    const int ta = t >> 4;
    float acc[4][4];
#pragma unroll
    for (int u = 0; u < 4; u++)
#pragma unroll
        for (int v = 0; v < 4; v++) acc[u][v] = 0.f;
    const int kmax = a0 + 64;        // K[k][a]=0 for k>a; a0 <= b0
    for (int k0 = 0; k0 < kmax; k0 += 64) {
#pragma unroll
        for (int q = 0; q < 4; q++) {
            const int f  = t + q * 256;
            const int kk = f >> 4;
            const int c4 = (f & 15) * 4;
            *reinterpret_cast<float4*>(&Ka[kk][c4]) =
                *reinterpret_cast<const float4*>(K + (k0 + kk) * NN + a0 + c4);
            *reinterpret_cast<float4*>(&Kb[kk][c4]) =
                *reinterpret_cast<const float4*>(K + (k0 + kk) * NN + b0 + c4);
        }
        __syncthreads();
#pragma unroll 8
        for (int kk = 0; kk < 64; kk++) {
            const float4 av = *reinterpret_cast<const float4*>(&Ka[kk][ta * 4]);
            const float4 bv = *reinterpret_cast<const float4*>(&Kb[kk][tb * 4]);
            const float a4[4] = {av.x, av.y, av.z, av.w};
            const float b4[4] = {bv.x, bv.y, bv.z, bv.w};
#pragma unroll
            for (int u = 0; u < 4; u++)
#pragma unroll
                for (int v = 0; v < 4; v++)
                    acc[u][v] = fmaf(a4[u], b4[v], acc[u][v]);
        }
        __syncthreads();
    }
#pragma unroll
    for (int u = 0; u < 4; u++) {
        float4 o;
        o.x = acc[u][0]; o.y = acc[u][1]; o.z = acc[u][2]; o.w = acc[u][3];
        *reinterpret_cast<float4*>(C + (a0 + ta * 4 + u) * NN + b0 + tb * 4) = o;
    }
    if (b0 > a0) {                   // mirror tile: C[b][a] = C[a][b], coalesced
#pragma unroll
        for (int v = 0; v < 4; v++) {
            float4 o;
            o.x = acc[0][v]; o.y = acc[1][v]; o.z = acc[2][v]; o.w = acc[3][v];
            *reinterpret_cast<float4*>(C + (b0 + tb * 4 + v) * NN + a0 + ta * 4) = o;
        }
    }
}

extern "C" void kernel_launch(void* const* d_in, const int* in_sizes, int n_in,
                              void* d_out, int out_size, void* d_ws, size_t ws_size,
                              hipStream_t stream)
{
    const float* x  = (const float*)d_in[0];
    const float* W1 = (const float*)d_in[1];
    const float* b1 = (const float*)d_in[2];
    const float* W2 = (const float*)d_in[3];
    const float* b2 = (const float*)d_in[4];
    const float* W3 = (const float*)d_in[5];
    const float* b3 = (const float*)d_in[6];
    float* Kmat = (float*)d_ws;                       // 2,359,296 B
    float* C    = (float*)d_out;

    const size_t kBytes  = (size_t)NN * NN * sizeof(float);
    const size_t wBytes  = 262144;                              // WF
    const size_t ecB     = (size_t)48 * 16384 * sizeof(ushort); // 1.5 MB
    const size_t needTab = kBytes + wBytes + ecB;               // ~4.1 MB
    const size_t needFB  = kBytes + wBytes;

    if (ws_size >= needTab) {
        ushort* WF  = (ushort*)((char*)d_ws + kBytes);
        ushort* ECF = (ushort*)((char*)d_ws + kBytes + wBytes);
        prep_all<<<1024, 256, 0, stream>>>(x, W1, W2, WF, ECF, Kmat);
        mlp_tab<<<dim3(6, NN), 256, 0, stream>>>(x, W1, b1, ECF, WF,
                                                 b2, W3, b3, Kmat);
    } else if (ws_size >= needFB) {
        hipMemsetAsync(Kmat, 0, kBytes, stream);
        ushort* WF = (ushort*)((char*)d_ws + kBytes);
        w2frag<<<64, 256, 0, stream>>>(W2, WF);
        mlp_pairs_reg<<<NPBLK2, 256, 0, stream>>>(x, W1, b1, WF, b2, W3, b3, Kmat);
    }
    ktk<<<dim3(NN / 64, NN / 64), 256, 0, stream>>>(Kmat, C);
}

// Round 22
// 163.953 us; speedup vs baseline: 1.1350x; 1.0419x over previous
//
#include <hip/hip_runtime.h>
#include <hip/hip_bf16.h>

#define NN 768
#define MD 1024
#define NPAIR 295296            // 768*769/2
#define NPBLK2 2307             // NPAIR / 128 (exact)

typedef __attribute__((ext_vector_type(8))) short s16x8;
typedef __attribute__((ext_vector_type(4))) float f32x4;
typedef __attribute__((ext_vector_type(2))) float f32x2;
typedef __attribute__((ext_vector_type(2))) __bf16 b16x2;

__device__ __forceinline__ ushort bf16_rn(float f) {
    uint u = __builtin_bit_cast(uint, f);
    u += 0x7FFFu + ((u >> 16) & 1u);
    return (ushort)(u >> 16);
}

// inverse triangular index: p -> (i,j), off(i) = i*(1537-i)/2, j = i + p - off(i)
__device__ __forceinline__ void ptoij(int p, int& io, int& jo) {
    const float disc = (float)(1537 * 1537 - 8 * p);
    int i = (int)((1537.0f - sqrtf(disc)) * 0.5f);
    i = i < 0 ? 0 : (i > 767 ? 767 : i);
    while (i > 0 && p < i * (1537 - i) / 2) --i;
    while (i < 767 && p >= (i + 1) * (1536 - i) / 2) ++i;
    io = i;
    jo = i + (p - i * (1537 - i) / 2);
}

// ---------- fused one-time prep: WF + zero-K (single launch) -------------------
// blocks [0,64):   W2 -> bf16 FRAGMENT-major WF (R14/R16-proven layout)
// blocks [64,640): zero Kmat (576 blocks x 256 thr x 16B = 2,359,296 B)
__global__ __launch_bounds__(256) void prep_all(
    const float* __restrict__ W2, ushort* __restrict__ WF,
    float* __restrict__ Kz)
{
    const int b = blockIdx.x;
    if (b < 64) {                                    // --- w2frag ---
        const int id = b * 256 + threadIdx.x;        // 0..16383
        const int lane = id & 63;
        const int f = id >> 6;                       // 0..255
        const int tn = f & 7;
        const int ks = (f >> 3) & 1;
        const int c  = f >> 4;
        const int k = tn * 16 + (lane & 15);
        const int m = c * 64 + ks * 32 + (lane >> 4) * 8;
        const float4 a = *reinterpret_cast<const float4*>(W2 + k * MD + m);
        const float4 bb = *reinterpret_cast<const float4*>(W2 + k * MD + m + 4);
        const float w[8] = {a.x, a.y, a.z, a.w, bb.x, bb.y, bb.z, bb.w};
        s16x8 h;
#pragma unroll
        for (int e = 0; e < 8; ++e) h[e] = (short)bf16_rn(w[e]);
        *reinterpret_cast<s16x8*>(WF + id * 8) = h;
    } else {                                         // --- zero K ---
        const int id = (b - 64) * 256 + threadIdx.x;
        *reinterpret_cast<f32x4*>(Kz + id * 4) = (f32x4){0.f, 0.f, 0.f, 0.f};
    }
}

// ---- macros (ambient locals) — R16-proven --------------------------------------
// load one ks-half of a chunk's B-fragments into registers (8 coalesced 1KB loads)
#define LOADB(cc, ks)                                                        \
    {                                                                        \
        const ushort* wb_ = WF + (cc) * 8192 + (ks) * 4096 + lane * 8;       \
        _Pragma("unroll")                                                    \
        for (int tn_ = 0; tn_ < 8; ++tn_)                                    \
            bh[tn_] = *reinterpret_cast<const s16x8*>(wb_ + tn_ * 512);      \
    }

// weights in sa/sc/sb pre-scaled by -log2(e): sigma = rcp(1 + 2^u)
// one ks-half (32 m): its ~320cy of VALU covers the in-flight bh loads
#define SIG_HALF(cc, ks_)                                                    \
    {                                                                        \
        const int m0_ = (cc) * 64 + (ks_) * 32 + l4 * 8;                     \
        const f32x4 a0_ = *reinterpret_cast<const f32x4*>(&sa[m0_]);         \
        const f32x4 a1_ = *reinterpret_cast<const f32x4*>(&sa[m0_ + 4]);     \
        const f32x4 c0_ = *reinterpret_cast<const f32x4*>(&sc[m0_]);         \
        const f32x4 c1_ = *reinterpret_cast<const f32x4*>(&sc[m0_ + 4]);     \
        const f32x4 b0_ = *reinterpret_cast<const f32x4*>(&sb[m0_]);         \
        const f32x4 b1_ = *reinterpret_cast<const f32x4*>(&sb[m0_ + 4]);     \
        _Pragma("unroll")                                                    \
        for (int tm_ = 0; tm_ < 2; ++tm_) {                                  \
            const f32x2 xi2_ = (f32x2){xia[tm_], xia[tm_]};                  \
            const f32x2 xj2_ = (f32x2){xja[tm_], xja[tm_]};                  \
            const f32x2 one2_ = (f32x2){1.f, 1.f};                           \
            union { s16x8 v; uint u[4]; } fr_;                               \
            _Pragma("unroll")                                                \
            for (int h_ = 0; h_ < 4; ++h_) {                                 \
                f32x2 av_, cv_, bv_;                                         \
                if (h_ < 2) {                                                \
                    av_ = (f32x2){a0_[2 * h_], a0_[2 * h_ + 1]};             \
                    cv_ = (f32x2){c0_[2 * h_], c0_[2 * h_ + 1]};             \
                    bv_ = (f32x2){b0_[2 * h_], b0_[2 * h_ + 1]};             \
                } else {                                                     \
                    av_ = (f32x2){a1_[2 * h_ - 4], a1_[2 * h_ - 3]};         \
                    cv_ = (f32x2){c1_[2 * h_ - 4], c1_[2 * h_ - 3]};         \
                    bv_ = (f32x2){b1_[2 * h_ - 4], b1_[2 * h_ - 3]};         \
                }                                                            \
                const f32x2 u2_ = __builtin_elementwise_fma(                 \
                    xi2_, av_, __builtin_elementwise_fma(xj2_, cv_, bv_));   \
                f32x2 e2_;                                                   \
                e2_[0] = __builtin_amdgcn_exp2f(u2_[0]);                     \
                e2_[1] = __builtin_amdgcn_exp2f(u2_[1]);                     \
                const f32x2 t2_ = e2_ + one2_;                               \
                b16x2 p_;                                                    \
                p_.x = (__bf16)__builtin_amdgcn_rcpf(t2_[0]);                \
                p_.y = (__bf16)__builtin_amdgcn_rcpf(t2_[1]);                \
                fr_.u[h_] = __builtin_bit_cast(uint, p_);                    \
            }                                                                \
            ah[tm_] = fr_.v;                                                 \
        }                                                                    \
    }

#define MFMA_HALF()                                                          \
    {                                                                        \
        __builtin_amdgcn_s_setprio(1);                                       \
        _Pragma("unroll")                                                    \
        for (int tm_ = 0; tm_ < 2; ++tm_)                                    \
            _Pragma("unroll")                                                \
            for (int tn_ = 0; tn_ < 8; ++tn_)                                \
                acc[tm_][tn_] = __builtin_amdgcn_mfma_f32_16x16x32_bf16(     \
                    ah[tm_], bh[tn_], acc[tm_][tn_], 0, 0, 0);               \
        __builtin_amdgcn_s_setprio(0);                                       \
    }

// ---------- main (R16-proven, 145.7us): 32 pairs/wave, reg-direct W2, 0 barriers
// per chunk: SIGk0 (covers ks0 loads) -> MFMA0 -> issue ks1 loads ->
//            SIGk1 (covers ks1 loads) -> MFMA1 -> issue next ks0 loads
__global__ __launch_bounds__(256, 3) void mlp_pairs_reg(
    const float* __restrict__ x,
    const float* __restrict__ W1, const float* __restrict__ b1,
    const ushort* __restrict__ WF,
    const float* __restrict__ b2, const float* __restrict__ W3,
    const float* __restrict__ b3, float* __restrict__ K)
{
    __shared__ __align__(16) float sa[MD], sc[MD], sb[MD];   // 12 KB total

    const int t = threadIdx.x;
    const int lane = t & 63;
    const int l15 = lane & 15, l4 = lane >> 4;
    const int wv = t >> 6;

    const float NL2E = -1.4426950408889634f;
    for (int m = t; m < MD; m += 256) {
        const float2 w = reinterpret_cast<const float2*>(W1)[m];
        sa[m] = w.x * NL2E;
        sc[m] = w.y * NL2E;
        sb[m] = b1[m] * NL2E;
    }

    const int pairbase = blockIdx.x * 128 + wv * 32;

    float xia[2], xja[2];
#pragma unroll
    for (int tm = 0; tm < 2; ++tm) {
        const int p = pairbase + tm * 16 + l15;
        if (p < NPAIR) {
            int i, j;
            ptoij(p, i, j);
            xia[tm] = x[i];
            xja[tm] = x[j];
        } else {
            xia[tm] = 0.f;
            xja[tm] = 0.f;
        }
    }

    f32x4 acc[2][8];
#pragma unroll
    for (int a = 0; a < 2; ++a)
#pragma unroll
        for (int b = 0; b < 8; ++b) acc[a][b] = (f32x4){0.f, 0.f, 0.f, 0.f};

    s16x8 bh[8];
    LOADB(0, 0);                     // issue chunk0/ks0 frag loads (global->reg)
    __syncthreads();                 // sa/sc/sb ready (the ONLY block barrier)

    s16x8 ah[2];
    for (int c = 0; c < 16; ++c) {
        SIG_HALF(c, 0);              // VALU covers in-flight ks0 loads
        MFMA_HALF();                 // consumes bh=ks0
        LOADB(c, 1);                 // refill bh with ks1 frags
        SIG_HALF(c, 1);              // VALU covers ks1 loads
        MFMA_HALF();                 // consumes bh=ks1
        if (c < 15) LOADB(c + 1, 0); // next chunk ks0 flies under next SIG
    }

    // epilogue: v = sum_k W3[k]*relu(h2 + b2[k]) + b3; reduce over 16 lanes (k)
    float w3v[8], b2v[8];
#pragma unroll
    for (int tn = 0; tn < 8; ++tn) {
        const int k = tn * 16 + l15;
        w3v[tn] = W3[k];
        b2v[tn] = b2[k];
    }
    const float b3v = b3[0];
#pragma unroll
    for (int tm = 0; tm < 2; ++tm)
#pragma unroll
        for (int r = 0; r < 4; ++r) {
            float v = 0.f;
#pragma unroll
            for (int tn = 0; tn < 8; ++tn)
                v = fmaf(w3v[tn], fmaxf(acc[tm][tn][r] + b2v[tn], 0.f), v);
            v += __shfl_xor(v, 1, 16);
            v += __shfl_xor(v, 2, 16);
            v += __shfl_xor(v, 4, 16);
            v += __shfl_xor(v, 8, 16);
            if (l15 == 0) {
                const int p = pairbase + tm * 16 + l4 * 4 + r;
                if (p < NPAIR) {
                    int i, j;
                    ptoij(p, i, j);
                    K[i * NN + j] = v + b3v;
                }
            }
        }
}

// ---------- Kernel 2: C = K^T K, symmetric — compute upper tiles, mirror -------
__global__ __launch_bounds__(256) void ktk(const float* __restrict__ K,
                                           float* __restrict__ C)
{
    const int b0 = blockIdx.x * 64;
    const int a0 = blockIdx.y * 64;
    if (b0 < a0) return;             // C symmetric: only tiles with b0 >= a0
    __shared__ float Ka[64][68];
    __shared__ float Kb[64][68];
    const int t  = threadIdx.x;
    const int tb = t & 15;
    const int ta = t >> 4;
    float acc[4][4];
#pragma unroll
    for (int u = 0; u < 4; u++)
#pragma unroll
        for (int v = 0; v < 4; v++) acc[u][v] = 0.f;
    const int kmax = a0 + 64;        // K[k][a]=0 for k>a; a0 <= b0
    for (int k0 = 0; k0 < kmax; k0 += 64) {
#pragma unroll
        for (int q = 0; q < 4; q++) {
            const int f  = t + q * 256;
            const int kk = f >> 4;
            const int c4 = (f & 15) * 4;
            *reinterpret_cast<float4*>(&Ka[kk][c4]) =
                *reinterpret_cast<const float4*>(K + (k0 + kk) * NN + a0 + c4);
            *reinterpret_cast<float4*>(&Kb[kk][c4]) =
                *reinterpret_cast<const float4*>(K + (k0 + kk) * NN + b0 + c4);
        }
        __syncthreads();
#pragma unroll 8
        for (int kk = 0; kk < 64; kk++) {
            const float4 av = *reinterpret_cast<const float4*>(&Ka[kk][ta * 4]);
            const float4 bv = *reinterpret_cast<const float4*>(&Kb[kk][tb * 4]);
            const float a4[4] = {av.x, av.y, av.z, av.w};
            const float b4[4] = {bv.x, bv.y, bv.z, bv.w};
#pragma unroll
            for (int u = 0; u < 4; u++)
#pragma unroll
                for (int v = 0; v < 4; v++)
                    acc[u][v] = fmaf(a4[u], b4[v], acc[u][v]);
        }
        __syncthreads();
    }
#pragma unroll
    for (int u = 0; u < 4; u++) {
        float4 o;
        o.x = acc[u][0]; o.y = acc[u][1]; o.z = acc[u][2]; o.w = acc[u][3];
        *reinterpret_cast<float4*>(C + (a0 + ta * 4 + u) * NN + b0 + tb * 4) = o;
    }
    if (b0 > a0) {                   // mirror tile: C[b][a] = C[a][b], coalesced
#pragma unroll
        for (int v = 0; v < 4; v++) {
            float4 o;
            o.x = acc[0][v]; o.y = acc[1][v]; o.z = acc[2][v]; o.w = acc[3][v];
            *reinterpret_cast<float4*>(C + (b0 + tb * 4 + v) * NN + a0 + ta * 4) = o;
        }
    }
}

extern "C" void kernel_launch(void* const* d_in, const int* in_sizes, int n_in,
                              void* d_out, int out_size, void* d_ws, size_t ws_size,
                              hipStream_t stream)
{
    const float* x  = (const float*)d_in[0];
    const float* W1 = (const float*)d_in[1];
    const float* b1 = (const float*)d_in[2];
    const float* W2 = (const float*)d_in[3];
    const float* b2 = (const float*)d_in[4];
    const float* W3 = (const float*)d_in[5];
    const float* b3 = (const float*)d_in[6];
    float* Kmat = (float*)d_ws;                       // 2,359,296 B
    float* C    = (float*)d_out;

    const size_t kBytes = (size_t)NN * NN * sizeof(float);
    const size_t need   = kBytes + 262144;            // + WF bf16 frag-major

    if (ws_size >= need) {
        ushort* WF = (ushort*)((char*)d_ws + kBytes);
        prep_all<<<640, 256, 0, stream>>>(W2, WF, Kmat);
        mlp_pairs_reg<<<NPBLK2, 256, 0, stream>>>(x, W1, b1, WF, b2, W3, b3, Kmat);
    } else {
        hipMemsetAsync(Kmat, 0, kBytes, stream);      // (insufficient ws: degenerate)
    }
    ktk<<<dim3(NN / 64, NN / 64), 256, 0, stream>>>(Kmat, C);
}